// Round 1
// 308.398 us; speedup vs baseline: 1.0718x; 1.0718x over previous
//
#include <hip/hip_runtime.h>
#include <math.h>

#define T_DIM 8192
#define B_DIM 4
#define INDIM 512
#define DV 512
#define DK 64
#define CHUNK 128
#define NCH (T_DIM / CHUNK)     // 64
#define ROWS (T_DIM * B_DIM)    // 32768
#define NPAD 768                // 704 proj cols padded to 6x128
#define KCAT 192                // 128 intra + 64 state
#define EPSF 1e-8f

typedef float float4_t __attribute__((ext_vector_type(4)));
typedef short short8_t __attribute__((ext_vector_type(8)));
typedef _Float16 half8_t __attribute__((ext_vector_type(8)));

__device__ inline unsigned short f2bf(float f) {
  unsigned int u = __float_as_uint(f);
  unsigned int r = (u + 0x7fffu + ((u >> 16) & 1u)) >> 16;
  return (unsigned short)r;
}
__device__ inline float bf2f(unsigned short h) {
  return __uint_as_float(((unsigned int)h) << 16);
}
__device__ inline unsigned short f2h(float f) {
  _Float16 h = (_Float16)f;
  unsigned short u;
  __builtin_memcpy(&u, &h, 2);
  return u;
}

__device__ inline void gload16(const void* g, void* l) {
  __builtin_amdgcn_global_load_lds(
      (const __attribute__((address_space(1))) void*)g,
      (__attribute__((address_space(3))) void*)l, 16, 0, 0);
}

// ---------------------------------------------------------------------------
// C0: merged fp16 cast.  blocks [0,16384): x -> xh (fp16).
// blocks [16384,16768): padded concat weights -> wh (fp16) + bcat.
// ---------------------------------------------------------------------------
__global__ __launch_bounds__(256) void cast_kernel(
    const float* __restrict__ x,
    const float* __restrict__ Wv, const float* __restrict__ Wk,
    const float* __restrict__ Wq, const float* __restrict__ Wa,
    const float* __restrict__ bv, const float* __restrict__ bk,
    const float* __restrict__ bq, const float* __restrict__ ba,
    unsigned short* __restrict__ xh, unsigned short* __restrict__ wh,
    float* __restrict__ bcat)
{
  if (blockIdx.x < 16384) {
    const size_t i4 = ((size_t)blockIdx.x * 256 + threadIdx.x) * 4;
    const float4 v = *(const float4*)&x[i4];
    ushort4 h;
    h.x = f2h(v.x); h.y = f2h(v.y); h.z = f2h(v.z); h.w = f2h(v.w);
    *(ushort4*)&xh[i4] = h;
  } else {
    const int t = (blockIdx.x - 16384) * 256 + threadIdx.x;
    const size_t i4 = (size_t)t * 4;
    const int row = (int)(i4 >> 9);
    const int col = (int)(i4 & 511);
    float4 v = {0.f, 0.f, 0.f, 0.f};
    if (row < 512)      v = *(const float4*)&Wv[(size_t)row * INDIM + col];
    else if (row < 576) v = *(const float4*)&Wk[(size_t)(row - 512) * INDIM + col];
    else if (row < 640) v = *(const float4*)&Wq[(size_t)(row - 576) * INDIM + col];
    else if (row < 704) v = *(const float4*)&Wa[(size_t)(row - 640) * INDIM + col];
    ushort4 h;
    h.x = f2h(v.x); h.y = f2h(v.y); h.z = f2h(v.z); h.w = f2h(v.w);
    *(ushort4*)&wh[i4] = h;
    if (t < NPAD) {
      float b = 0.f;
      if (t < 512)      b = bv[t];
      else if (t < 576) b = bk[t - 512];
      else if (t < 640) b = bq[t - 576];
      else if (t < 704) b = ba[t - 640];
      bcat[t] = b;
    }
  }
}

// ---------------------------------------------------------------------------
// K1: fp16 MFMA projection GEMM (M=32768,K=512,N=768), fp32 accumulate.
// Round-6: double-buffered LDS with counted vmcnt(4) (T3/T4 minimum recipe,
// loads stay in flight across barriers), XCD-grouped block mapping so the 6
// column tiles of a row panel share one XCD's L2, and q written as coalesced
// fp32 to q_ws (scatter moved into prep_kernel).
// ---------------------------------------------------------------------------
__global__ __launch_bounds__(256) void proj_mfma_kernel(
    const unsigned short* __restrict__ xh, const unsigned short* __restrict__ wh,
    const float* __restrict__ bcat,
    float* __restrict__ v_ws, float* __restrict__ k_ws,
    float* __restrict__ q_ws, float* __restrict__ a_ws)
{
  __shared__ __align__(16) _Float16 Ah[2][128 * 32];
  __shared__ __align__(16) _Float16 Bh[2][128 * 32];

  // XCD-grouped swizzle: dispatch d -> XCD d&7 (round-robin).  XCD i owns
  // row panels [i*32, i*32+32); within an XCD the 6 column tiles of a panel
  // are adjacent, so a 128 KB xh panel is an L2 hit for 5 of its 6 readers.
  const int d     = blockIdx.x;
  const int grp   = d >> 3;                 // 0..191
  const int ytile = (d & 7) * 32 + grp / 6; // 0..255
  const int xtile = grp % 6;                // 0..5
  const int r0 = ytile * 128;
  const int c0 = xtile * 128;

  const int tid  = threadIdx.x;
  const int wave = tid >> 6, lane = tid & 63;
  const int wm   = (wave & 1) * 64, wn = (wave >> 1) * 64;
  const int fm   = lane & 15;
  const int fk   = (lane >> 4) * 8;

  float4_t acc[4][4];
#pragma unroll
  for (int i = 0; i < 4; ++i)
#pragma unroll
    for (int j = 0; j < 4; ++j) acc[i][j] = (float4_t)0.0f;

  const int srow = tid >> 2;           // 0..63
  const int scol = (tid & 3) * 8;      // 0,8,16,24

  const unsigned short* pA0 = xh + (size_t)(r0 + srow) * INDIM + scol;
  const unsigned short* pA1 = xh + (size_t)(r0 + 64 + srow) * INDIM + scol;
  const unsigned short* pB0 = wh + (size_t)(c0 + srow) * INDIM + scol;
  const unsigned short* pB1 = wh + (size_t)(c0 + 64 + srow) * INDIM + scol;

  auto stage = [&](int buf, int k0) {
    gload16(pA0 + k0, &Ah[buf][tid * 8]);
    gload16(pA1 + k0, &Ah[buf][(256 + tid) * 8]);
    gload16(pB0 + k0, &Bh[buf][tid * 8]);
    gload16(pB1 + k0, &Bh[buf][(256 + tid) * 8]);
  };

  auto compute = [&](int buf) {
    half8_t a[4], b[4];
#pragma unroll
    for (int i = 0; i < 4; ++i)
      a[i] = *(const half8_t*)&Ah[buf][(wm + i * 16 + fm) * 32 + fk];
#pragma unroll
    for (int j = 0; j < 4; ++j)
      b[j] = *(const half8_t*)&Bh[buf][(wn + j * 16 + fm) * 32 + fk];
#pragma unroll
    for (int i = 0; i < 4; ++i)
#pragma unroll
      for (int j = 0; j < 4; ++j)
        acc[i][j] = __builtin_amdgcn_mfma_f32_16x16x32_f16(a[i], b[j], acc[i][j], 0, 0, 0);
  };

  // prologue: stage tile 0
  stage(0, 0);
  int cur = 0;
  // main loop: 15 pipelined steps.  vmcnt(4) keeps the just-issued 4 loads
  // (next tile) in flight; barrier #1 makes "my prev-stage done" collective;
  // barrier #2 protects buf[cur^1] before the next iteration restages it.
  for (int t = 0; t < 15; ++t) {
    stage(cur ^ 1, (t + 1) * 32);
    asm volatile("s_waitcnt vmcnt(4)" ::: "memory");
    __builtin_amdgcn_s_barrier();
    compute(cur);
    __builtin_amdgcn_s_barrier();
    cur ^= 1;
  }
  asm volatile("s_waitcnt vmcnt(0)" ::: "memory");
  __builtin_amdgcn_s_barrier();
  compute(cur);

  // epilogue: all four projections written coalesced (q now fp32 to q_ws)
#pragma unroll
  for (int j = 0; j < 4; ++j) {
    const int col = c0 + wn + j * 16 + fm;
    if (col >= 704) continue;
    const float bias = bcat[col];
#pragma unroll
    for (int i = 0; i < 4; ++i) {
#pragma unroll
      for (int r = 0; r < 4; ++r) {
        const int row = r0 + wm + i * 16 + (lane >> 4) * 4 + r;  // row = t*4+b
        const float val = acc[i][j][r] + bias;
        if (col < 512) {
          v_ws[(size_t)row * DV + col] = val;
        } else if (col < 576) {
          k_ws[(size_t)row * DK + col - 512] = val;
        } else if (col < 640) {
          q_ws[(size_t)row * DK + col - 576] = val;
        } else {
          a_ws[(size_t)row * DK + col - 640] = 1.0f / (1.0f + expf(-val));
        }
      }
    }
  }
}

// ---------------------------------------------------------------------------
// K2: per-(c,b) chunk prep.  LDS-resident cumprod, then coalesced
// q_t (fp32 q_ws -> Acat hi/lo write) and k_t (k_ws fp32 RMW) passes.
// grid (NCH, B_DIM).
// ---------------------------------------------------------------------------
__global__ __launch_bounds__(256) void prep_kernel(
    const float* __restrict__ a_ws, float* __restrict__ k_ws,
    const float* __restrict__ q_ws,
    unsigned short* __restrict__ Acat_h, unsigned short* __restrict__ Acat_l,
    float* __restrict__ pend)
{
  __shared__ float pal[CHUNK][DK];    // 32 KB: alpha -> cumprod p
  const int c = blockIdx.x, b = blockIdx.y;
  const int cb = c * B_DIM + b;
  const int tid = threadIdx.x;

#pragma unroll
  for (int i = 0; i < 8; ++i) {
    const int f = (i * 256 + tid) * 4;       // 0..8191
    const int t = f >> 6, n0 = f & 63;
    const float4 av = *(const float4*)&a_ws[(size_t)(c * CHUNK + t) * 256 + b * 64 + n0];
    *(float4*)&pal[t][n0] = av;
  }
  __syncthreads();

  if (tid < 64) {
    float p = 1.0f;
#pragma unroll 4
    for (int t = 0; t < CHUNK; ++t) {
      p *= fmaxf(pal[t][tid], EPSF);
      pal[t][tid] = p;
    }
    pend[c * 256 + b * 64 + tid] = p;
  }
  __syncthreads();

#pragma unroll
  for (int i = 0; i < 8; ++i) {
    const int f = (i * 256 + tid) * 4;
    const int t = f >> 6, n0 = f & 63;
    const float4 qv = *(const float4*)&q_ws[(size_t)(c * CHUNK + t) * 256 + b * 64 + n0];
    const size_t qa = ((size_t)cb * CHUNK + t) * KCAT + 128 + n0;
    float q0 = qv.x * pal[t][n0 + 0];
    float q1 = qv.y * pal[t][n0 + 1];
    float q2 = qv.z * pal[t][n0 + 2];
    float q3 = qv.w * pal[t][n0 + 3];
    ushort4 h, l;
    h.x = f2bf(q0); l.x = f2bf(q0 - bf2f(h.x));
    h.y = f2bf(q1); l.y = f2bf(q1 - bf2f(h.y));
    h.z = f2bf(q2); l.z = f2bf(q2 - bf2f(h.z));
    h.w = f2bf(q3); l.w = f2bf(q3 - bf2f(h.w));
    *(ushort4*)&Acat_h[qa] = h;
    *(ushort4*)&Acat_l[qa] = l;
  }

#pragma unroll
  for (int i = 0; i < 8; ++i) {
    const int f = (i * 256 + tid) * 4;
    const int t = f >> 6, n0 = f & 63;
    const size_t ka = (size_t)(c * CHUNK + t) * 256 + b * 64 + n0;
    float4 kv = *(const float4*)&k_ws[ka];
    kv.x = kv.x / (pal[t][n0 + 0] + EPSF);
    kv.y = kv.y / (pal[t][n0 + 1] + EPSF);
    kv.z = kv.z / (pal[t][n0 + 2] + EPSF);
    kv.w = kv.w / (pal[t][n0 + 3] + EPSF);
    *(float4*)&k_ws[ka] = kv;
  }
}

// ---------------------------------------------------------------------------
// K4b: transpose-cast v -> Bt hi/lo, layout [(c,b)][d][s] bf16.  (round-5)
// ---------------------------------------------------------------------------
__global__ __launch_bounds__(256) void vt_kernel(
    const float* __restrict__ v_ws,
    unsigned short* __restrict__ Bt_h, unsigned short* __restrict__ Bt_l)
{
  __shared__ float Ts[CHUNK][65];
  const int c = blockIdx.x, b = blockIdx.y, dblk = blockIdx.z;
  const int cb = c * B_DIM + b;
  const int d0 = dblk * 64;
  const int tid = threadIdx.x;
#pragma unroll
  for (int q = 0; q < 8; ++q) {
    const int idx = (q * 256 + tid) * 4;       // 0..8191
    const int s = idx >> 6, dd = idx & 63;
    const float4 v = *(const float4*)&v_ws[(size_t)((c * CHUNK + s) * B_DIM + b) * DV + d0 + dd];
    Ts[s][dd + 0] = v.x; Ts[s][dd + 1] = v.y;
    Ts[s][dd + 2] = v.z; Ts[s][dd + 3] = v.w;
  }
  __syncthreads();
#pragma unroll
  for (int q = 0; q < 8; ++q) {
    const int idx = (q * 256 + tid) * 4;
    const int dd = idx >> 7, s0 = idx & 127;
    float v0 = Ts[s0 + 0][dd], v1 = Ts[s0 + 1][dd];
    float v2 = Ts[s0 + 2][dd], v3 = Ts[s0 + 3][dd];
    ushort4 h, l;
    h.x = f2bf(v0); l.x = f2bf(v0 - bf2f(h.x));
    h.y = f2bf(v1); l.y = f2bf(v1 - bf2f(h.y));
    h.z = f2bf(v2); l.z = f2bf(v2 - bf2f(h.z));
    h.w = f2bf(v3); l.w = f2bf(v3 - bf2f(h.w));
    const size_t oa = ((size_t)cb * DV + d0 + dd) * CHUNK + s0;
    *(ushort4*)&Bt_h[oa] = h;
    *(ushort4*)&Bt_l[oa] = l;
  }
}

// ---------------------------------------------------------------------------
// K3: wchunk via MFMA.  W[d][n] = (sum_t v^T[d][t]*k_t[t][n]) * pend[n].
// ---------------------------------------------------------------------------
__global__ __launch_bounds__(256) void wchunk_mfma_kernel(
    const unsigned short* __restrict__ Bt_h, const unsigned short* __restrict__ Bt_l,
    const float* __restrict__ k_ws, const float* __restrict__ pend,
    float* __restrict__ W_ws)
{
  __shared__ __align__(16) unsigned short Ah[128 * 32];
  __shared__ __align__(16) unsigned short Al[128 * 32];

  const int c = blockIdx.x, b = blockIdx.y, dt = blockIdx.z;
  const int cb = c * B_DIM + b;
  const int tid  = threadIdx.x;
  const int wave = tid >> 6, lane = tid & 63;
  const int wm   = (wave & 1) * 64;
  const int wn   = (wave >> 1) * 32;
  const int fm   = lane & 15;
  const int fk   = (lane >> 4) * 8;

  const unsigned short* Ab_h = Bt_h + ((size_t)cb * DV + dt * 128) * CHUNK;
  const unsigned short* Ab_l = Bt_l + ((size_t)cb * DV + dt * 128) * CHUNK;

  float4_t acc[4][2];
#pragma unroll
  for (int i = 0; i < 4; ++i)
#pragma unroll
    for (int j = 0; j < 2; ++j) acc[i][j] = (float4_t)0.0f;

  for (int ks = 0; ks < 4; ++ks) {
    const int k0 = ks * 32;
#pragma unroll
    for (int q = 0; q < 2; ++q) {
      const int flat = (q * 256 + tid) * 8;
      const int row = flat >> 5, col = flat & 31;
      gload16(&Ab_h[(size_t)row * CHUNK + k0 + col], &Ah[flat]);
      gload16(&Ab_l[(size_t)row * CHUNK + k0 + col], &Al[flat]);
    }

    short8_t b_hi[2], b_lo[2];
#pragma unroll
    for (int j = 0; j < 2; ++j) {
      const int n = wn + j * 16 + fm;
#pragma unroll
      for (int e = 0; e < 8; ++e) {
        const float kv = k_ws[(size_t)(c * CHUNK + k0 + fk + e) * 256 + b * 64 + n];
        const unsigned short h = f2bf(kv);
        b_hi[j][e] = (short)h;
        b_lo[j][e] = (short)f2bf(kv - bf2f(h));
      }
    }
    __syncthreads();

    short8_t a_hi[4], a_lo[4];
#pragma unroll
    for (int i = 0; i < 4; ++i) {
      const int ar = (wm + i * 16 + fm) * 32 + fk;
      a_hi[i] = *(const short8_t*)&Ah[ar];
      a_lo[i] = *(const short8_t*)&Al[ar];
    }
#pragma unroll
    for (int i = 0; i < 4; ++i)
#pragma unroll
      for (int j = 0; j < 2; ++j) {
        acc[i][j] = __builtin_amdgcn_mfma_f32_16x16x32_bf16(a_hi[i], b_hi[j], acc[i][j], 0, 0, 0);
        acc[i][j] = __builtin_amdgcn_mfma_f32_16x16x32_bf16(a_lo[i], b_hi[j], acc[i][j], 0, 0, 0);
        acc[i][j] = __builtin_amdgcn_mfma_f32_16x16x32_bf16(a_hi[i], b_lo[j], acc[i][j], 0, 0, 0);
      }
    __syncthreads();
  }

#pragma unroll
  for (int j = 0; j < 2; ++j) {
    const int n = wn + j * 16 + fm;
    const float pj = pend[c * 256 + b * 64 + n];
#pragma unroll
    for (int i = 0; i < 4; ++i) {
#pragma unroll
      for (int r = 0; r < 4; ++r) {
        const int d = dt * 128 + wm + i * 16 + (lane >> 4) * 4 + r;
        W_ws[((size_t)cb * DV + d) * DK + n] = acc[i][j][r] * pj;
      }
    }
  }
}

// ---------------------------------------------------------------------------
// K4: sequential state scan over chunks (in place; W_ws[c] <- S_c pre-update)
// ---------------------------------------------------------------------------
__global__ __launch_bounds__(256) void scan_kernel(
    float* __restrict__ W_ws, const float* __restrict__ pend)
{
  const int flat = blockIdx.x * 256 + threadIdx.x;
  const int n = flat & 63;
  const int bd = flat >> 6;
  const int b = bd >> 9;
  float s = 0.0f;
  for (int c = 0; c < NCH; ++c) {
    const int off = c * 131072 + flat;
    const float w = W_ws[off];
    W_ws[off] = s;
    s = s * pend[c * 256 + b * 64 + n] + w;
  }
}

// ---------------------------------------------------------------------------
// K5: A = tril(q_t @ k_t^T) via MFMA.  Writes Acat cols [0,128) hi/lo.
// ---------------------------------------------------------------------------
__global__ __launch_bounds__(256) void score_mfma_kernel(
    const float* __restrict__ k_ws,
    unsigned short* __restrict__ Acat_h, unsigned short* __restrict__ Acat_l)
{
  __shared__ __align__(16) unsigned short Ah[128 * 32];
  __shared__ __align__(16) unsigned short Al[128 * 32];
  __shared__ __align__(16) unsigned short Bh[128 * 32];
  __shared__ __align__(16) unsigned short Bl[128 * 32];

  const int c = blockIdx.x, b = blockIdx.y;
  const int cb = c * B_DIM + b;
  const int tid  = threadIdx.x;
  const int wave = tid >> 6, lane = tid & 63;
  const int wm   = (wave & 1) * 64, wn = (wave >> 1) * 64;
  const int fm   = lane & 15;
  const int fk   = (lane >> 4) * 8;

  const unsigned short* Aq_h = Acat_h + (size_t)cb * CHUNK * KCAT + 128;
  const unsigned short* Aq_l = Acat_l + (size_t)cb * CHUNK * KCAT + 128;

  float4_t acc[4][4];
#pragma unroll
  for (int i = 0; i < 4; ++i)
#pragma unroll
    for (int j = 0; j < 4; ++j) acc[i][j] = (float4_t)0.0f;

  for (int ks = 0; ks < 2; ++ks) {
    const int k0 = ks * 32;
#pragma unroll
    for (int q = 0; q < 2; ++q) {
      const int flat = (q * 256 + tid) * 8;
      const int row = flat >> 5, col = flat & 31;
      gload16(&Aq_h[(size_t)row * KCAT + k0 + col], &Ah[flat]);
      gload16(&Aq_l[(size_t)row * KCAT + k0 + col], &Al[flat]);
    }
#pragma unroll
    for (int q = 0; q < 4; ++q) {
      const int flat = (q * 256 + tid) * 4;
      const int s = flat >> 5, n0 = flat & 31;
      const float4 kv = *(const float4*)&k_ws[(size_t)(c * CHUNK + s) * 256 + b * 64 + k0 + n0];
      ushort4 h, l;
      h.x = f2bf(kv.x); l.x = f2bf(kv.x - bf2f(h.x));
      h.y = f2bf(kv.y); l.y = f2bf(kv.y - bf2f(h.y));
      h.z = f2bf(kv.z); l.z = f2bf(kv.z - bf2f(h.z));
      h.w = f2bf(kv.w); l.w = f2bf(kv.w - bf2f(h.w));
      *(ushort4*)&Bh[s * 32 + n0] = h;
      *(ushort4*)&Bl[s * 32 + n0] = l;
    }
    __syncthreads();

    short8_t a_hi[4], a_lo[4], b_hi[4], b_lo[4];
#pragma unroll
    for (int i = 0; i < 4; ++i) {
      const int ar = (wm + i * 16 + fm) * 32 + fk;
      a_hi[i] = *(const short8_t*)&Ah[ar];
      a_lo[i] = *(const short8_t*)&Al[ar];
    }
#pragma unroll
    for (int j = 0; j < 4; ++j) {
      const int br = (wn + j * 16 + fm) * 32 + fk;
      b_hi[j] = *(const short8_t*)&Bh[br];
      b_lo[j] = *(const short8_t*)&Bl[br];
    }
#pragma unroll
    for (int i = 0; i < 4; ++i)
#pragma unroll
      for (int j = 0; j < 4; ++j) {
        acc[i][j] = __builtin_amdgcn_mfma_f32_16x16x32_bf16(a_hi[i], b_hi[j], acc[i][j], 0, 0, 0);
        acc[i][j] = __builtin_amdgcn_mfma_f32_16x16x32_bf16(a_lo[i], b_hi[j], acc[i][j], 0, 0, 0);
        acc[i][j] = __builtin_amdgcn_mfma_f32_16x16x32_bf16(a_hi[i], b_lo[j], acc[i][j], 0, 0, 0);
      }
    __syncthreads();
  }

#pragma unroll
  for (int j = 0; j < 4; ++j) {
    const int s = wn + j * 16 + fm;
#pragma unroll
    for (int i = 0; i < 4; ++i) {
#pragma unroll
      for (int r = 0; r < 4; ++r) {
        const int t = wm + i * 16 + (lane >> 4) * 4 + r;
        const float vv = (s <= t) ? acc[i][j][r] : 0.0f;
        const unsigned short h = f2bf(vv);
        const size_t oa = ((size_t)cb * CHUNK + t) * KCAT + s;
        Acat_h[oa] = h;
        Acat_l[oa] = f2bf(vv - bf2f(h));
      }
    }
  }
}

// ---------------------------------------------------------------------------
// K6: y = [A|q_t] @ [v ; S^T]  via split-bf16 MFMA.  M=128(t) N=128(d-tile)
// K=192.  Steps 0..3 stage B from Bt; steps 4,5 convert S fp32.
// ---------------------------------------------------------------------------
__global__ __launch_bounds__(256) void out_mfma_kernel(
    const unsigned short* __restrict__ Acat_h, const unsigned short* __restrict__ Acat_l,
    const unsigned short* __restrict__ Bt_h, const unsigned short* __restrict__ Bt_l,
    const float* __restrict__ W_ws, float* __restrict__ out)
{
  __shared__ __align__(16) unsigned short Ah[128 * 32];
  __shared__ __align__(16) unsigned short Al[128 * 32];
  __shared__ __align__(16) unsigned short Bh[128 * 32];
  __shared__ __align__(16) unsigned short Bl[128 * 32];

  const int c = blockIdx.x, b = blockIdx.y, nt = blockIdx.z;
  const int cb = c * B_DIM + b;
  const int tid  = threadIdx.x;
  const int wave = tid >> 6, lane = tid & 63;
  const int wm   = (wave & 1) * 64, wn = (wave >> 1) * 64;
  const int fm   = lane & 15;
  const int fk   = (lane >> 4) * 8;

  const unsigned short* Ab_h = Acat_h + (size_t)cb * CHUNK * KCAT;
  const unsigned short* Ab_l = Acat_l + (size_t)cb * CHUNK * KCAT;
  const unsigned short* Bb_h = Bt_h + ((size_t)cb * DV + nt * 128) * CHUNK;
  const unsigned short* Bb_l = Bt_l + ((size_t)cb * DV + nt * 128) * CHUNK;
  const float* Sb = W_ws + ((size_t)cb * DV + nt * 128) * DK;

  float4_t acc[4][4];
#pragma unroll
  for (int i = 0; i < 4; ++i)
#pragma unroll
    for (int j = 0; j < 4; ++j) acc[i][j] = (float4_t)0.0f;

  for (int ks = 0; ks < 6; ++ks) {
    const int k0 = ks * 32;
#pragma unroll
    for (int q = 0; q < 2; ++q) {
      const int flat = q * 2048 + tid * 8;
      const int row = flat >> 5, col = flat & 31;
      gload16(&Ab_h[(size_t)row * KCAT + k0 + col], &Ah[flat]);
      gload16(&Ab_l[(size_t)row * KCAT + k0 + col], &Al[flat]);
    }
    if (ks < 4) {
#pragma unroll
      for (int q = 0; q < 2; ++q) {
        const int flat = q * 2048 + tid * 8;
        const int row = flat >> 5, col = flat & 31;
        gload16(&Bb_h[(size_t)row * CHUNK + k0 + col], &Bh[flat]);
        gload16(&Bb_l[(size_t)row * CHUNK + k0 + col], &Bl[flat]);
      }
    } else {
#pragma unroll
      for (int q = 0; q < 4; ++q) {
        const int flat = (q * 256 + tid) * 4;
        const int r = flat >> 5, n0 = flat & 31;
        const float4 sv = *(const float4*)&Sb[(size_t)r * DK + (k0 - 128) + n0];
        ushort4 h, l;
        h.x = f2bf(sv.x); l.x = f2bf(sv.x - bf2f(h.x));
        h.y = f2bf(sv.y); l.y = f2bf(sv.y - bf2f(h.y));
        h.z = f2bf(sv.z); l.z = f2bf(sv.z - bf2f(h.z));
        h.w = f2bf(sv.w); l.w = f2bf(sv.w - bf2f(h.w));
        *(ushort4*)&Bh[r * 32 + n0] = h;
        *(ushort4*)&Bl[r * 32 + n0] = l;
      }
    }
    __syncthreads();

    short8_t a_hi[4], a_lo[4], b_hi[4], b_lo[4];
#pragma unroll
    for (int i = 0; i < 4; ++i) {
      const int ar = (wm + i * 16 + fm) * 32 + fk;
      a_hi[i] = *(const short8_t*)&Ah[ar];
      a_lo[i] = *(const short8_t*)&Al[ar];
    }
#pragma unroll
    for (int j = 0; j < 4; ++j) {
      const int br = (wn + j * 16 + fm) * 32 + fk;
      b_hi[j] = *(const short8_t*)&Bh[br];
      b_lo[j] = *(const short8_t*)&Bl[br];
    }
#pragma unroll
    for (int i = 0; i < 4; ++i)
#pragma unroll
      for (int j = 0; j < 4; ++j) {
        acc[i][j] = __builtin_amdgcn_mfma_f32_16x16x32_bf16(a_hi[i], b_hi[j], acc[i][j], 0, 0, 0);
        acc[i][j] = __builtin_amdgcn_mfma_f32_16x16x32_bf16(a_lo[i], b_hi[j], acc[i][j], 0, 0, 0);
        acc[i][j] = __builtin_amdgcn_mfma_f32_16x16x32_bf16(a_hi[i], b_lo[j], acc[i][j], 0, 0, 0);
      }
    __syncthreads();
  }

#pragma unroll
  for (int j = 0; j < 4; ++j) {
    const int d = nt * 128 + wn + j * 16 + fm;
#pragma unroll
    for (int i = 0; i < 4; ++i) {
#pragma unroll
      for (int r = 0; r < 4; ++r) {
        const int t = c * CHUNK + wm + i * 16 + (lane >> 4) * 4 + r;
        out[((size_t)t * B_DIM + b) * DV + d] = acc[i][j][r];
      }
    }
  }
}

// ---------------------------------------------------------------------------
extern "C" void kernel_launch(void* const* d_in, const int* in_sizes, int n_in,
                              void* d_out, int out_size, void* d_ws, size_t ws_size,
                              hipStream_t stream)
{
  const float* x  = (const float*)d_in[0];
  const float* Wv = (const float*)d_in[1];
  const float* bv = (const float*)d_in[2];
  const float* Wk = (const float*)d_in[3];
  const float* bk = (const float*)d_in[4];
  const float* Wq = (const float*)d_in[5];
  const float* bq = (const float*)d_in[6];
  const float* Wa = (const float*)d_in[7];
  const float* ba = (const float*)d_in[8];
  float* out = (float*)d_out;

  // ---- workspace layout (unchanged footprint; q_ws aliased into uni) ----
  float* ws   = (float*)d_ws;
  float* v_ws = ws;                                         // 16,777,216 f
  float* k_ws = v_ws + (size_t)ROWS * DV;                   //  2,097,152 f
  float* a_ws = k_ws + (size_t)ROWS * DK;                   //  2,097,152 f
  float* pend = a_ws + (size_t)ROWS * DK;                   //     16,384 f
  float* W_ws = pend + NCH * B_DIM * DK;                    //  8,388,608 f
  float* bcat = W_ws + (size_t)NCH * B_DIM * DV * DK;       //        768 f
  unsigned short* Acat_h = (unsigned short*)(bcat + NPAD);  //  6,291,456 us
  unsigned short* Acat_l = Acat_h + (size_t)NCH * B_DIM * CHUNK * KCAT;
  unsigned short* uni = Acat_l + (size_t)NCH * B_DIM * CHUNK * KCAT;
  // union A: fp16 proj staging (dead after proj_mfma)
  unsigned short* xh = uni;                                 // 16,777,216 us
  unsigned short* wh = xh + (size_t)ROWS * INDIM;           //    393,216 us
  // q_ws: fp32 q staging, aliased at uni+36MiB (beyond xh+wh's 32.75 MiB,
  // inside Bt's 64 MiB span; consumed by prep BEFORE vt writes Bt).
  float* q_ws = (float*)(uni + (size_t)18 * 1024 * 1024);   //  2,097,152 f
  // union B: v^T split-bf16 (written by vt_kernel after prep) — 64 MiB
  unsigned short* Bt_h = uni;
  unsigned short* Bt_l = Bt_h + (size_t)NCH * B_DIM * DV * CHUNK;

  cast_kernel<<<16384 + 384, 256, 0, stream>>>(
      x, Wv, Wk, Wq, Wa, bv, bk, bq, ba, xh, wh, bcat);
  proj_mfma_kernel<<<(ROWS / 128) * (NPAD / 128), 256, 0, stream>>>(
      xh, wh, bcat, v_ws, k_ws, q_ws, a_ws);
  prep_kernel<<<dim3(NCH, B_DIM), 256, 0, stream>>>(
      a_ws, k_ws, q_ws, Acat_h, Acat_l, pend);
  vt_kernel<<<dim3(NCH, B_DIM, 8), 256, 0, stream>>>(v_ws, Bt_h, Bt_l);
  wchunk_mfma_kernel<<<dim3(NCH, B_DIM, 4), 256, 0, stream>>>(
      Bt_h, Bt_l, k_ws, pend, W_ws);
  scan_kernel<<<(B_DIM * DV * DK) / 256, 256, 0, stream>>>(W_ws, pend);
  score_mfma_kernel<<<dim3(NCH, B_DIM), 256, 0, stream>>>(
      k_ws, Acat_h, Acat_l);
  out_mfma_kernel<<<dim3(NCH, B_DIM, 4), 256, 0, stream>>>(
      Acat_h, Acat_l, Bt_h, Bt_l, W_ws, out);
}

// Round 3
// 304.042 us; speedup vs baseline: 1.0872x; 1.0143x over previous
//
#include <hip/hip_runtime.h>
#include <math.h>

#define T_DIM 8192
#define B_DIM 4
#define INDIM 512
#define DV 512
#define DK 64
#define CHUNK 128
#define NCH (T_DIM / CHUNK)     // 64
#define ROWS (T_DIM * B_DIM)    // 32768
#define NPAD 768                // 704 proj cols padded to 6x128
#define KCAT 192                // 128 intra + 64 state
#define EPSF 1e-8f

typedef float float4_t __attribute__((ext_vector_type(4)));
typedef short short8_t __attribute__((ext_vector_type(8)));
typedef _Float16 half8_t __attribute__((ext_vector_type(8)));

__device__ inline unsigned short f2bf(float f) {
  unsigned int u = __float_as_uint(f);
  unsigned int r = (u + 0x7fffu + ((u >> 16) & 1u)) >> 16;
  return (unsigned short)r;
}
__device__ inline float bf2f(unsigned short h) {
  return __uint_as_float(((unsigned int)h) << 16);
}
__device__ inline unsigned short f2h(float f) {
  _Float16 h = (_Float16)f;
  unsigned short u;
  __builtin_memcpy(&u, &h, 2);
  return u;
}

__device__ inline void gload16(const void* g, void* l) {
  __builtin_amdgcn_global_load_lds(
      (const __attribute__((address_space(1))) void*)g,
      (__attribute__((address_space(3))) void*)l, 16, 0, 0);
}

// ---------------------------------------------------------------------------
// C0: merged fp16 cast.  blocks [0,16384): x -> xh (fp16).
// blocks [16384,16768): padded concat weights -> wh (fp16) + bcat.
// ---------------------------------------------------------------------------
__global__ __launch_bounds__(256) void cast_kernel(
    const float* __restrict__ x,
    const float* __restrict__ Wv, const float* __restrict__ Wk,
    const float* __restrict__ Wq, const float* __restrict__ Wa,
    const float* __restrict__ bv, const float* __restrict__ bk,
    const float* __restrict__ bq, const float* __restrict__ ba,
    unsigned short* __restrict__ xh, unsigned short* __restrict__ wh,
    float* __restrict__ bcat)
{
  if (blockIdx.x < 16384) {
    const size_t i4 = ((size_t)blockIdx.x * 256 + threadIdx.x) * 4;
    const float4 v = *(const float4*)&x[i4];
    ushort4 h;
    h.x = f2h(v.x); h.y = f2h(v.y); h.z = f2h(v.z); h.w = f2h(v.w);
    *(ushort4*)&xh[i4] = h;
  } else {
    const int t = (blockIdx.x - 16384) * 256 + threadIdx.x;
    const size_t i4 = (size_t)t * 4;
    const int row = (int)(i4 >> 9);
    const int col = (int)(i4 & 511);
    float4 v = {0.f, 0.f, 0.f, 0.f};
    if (row < 512)      v = *(const float4*)&Wv[(size_t)row * INDIM + col];
    else if (row < 576) v = *(const float4*)&Wk[(size_t)(row - 512) * INDIM + col];
    else if (row < 640) v = *(const float4*)&Wq[(size_t)(row - 576) * INDIM + col];
    else if (row < 704) v = *(const float4*)&Wa[(size_t)(row - 640) * INDIM + col];
    ushort4 h;
    h.x = f2h(v.x); h.y = f2h(v.y); h.z = f2h(v.z); h.w = f2h(v.w);
    *(ushort4*)&wh[i4] = h;
    if (t < NPAD) {
      float b = 0.f;
      if (t < 512)      b = bv[t];
      else if (t < 576) b = bk[t - 512];
      else if (t < 640) b = bq[t - 576];
      else if (t < 704) b = ba[t - 640];
      bcat[t] = b;
    }
  }
}

// ---------------------------------------------------------------------------
// K1: fp16 MFMA projection GEMM (M=32768,K=512,N=768), fp32 accumulate.
// 3-buffer ring, depth-2 prefetch (vmcnt(8) steady state), LDS 48 KB ->
// 3 blocks/CU.  XCD-grouped mapping kept (proved -13 MB FETCH in round 1).
// ---------------------------------------------------------------------------
__global__ __launch_bounds__(256) void proj_mfma_kernel(
    const unsigned short* __restrict__ xh, const unsigned short* __restrict__ wh,
    const float* __restrict__ bcat,
    float* __restrict__ v_ws, float* __restrict__ k_ws,
    float* __restrict__ q_ws, float* __restrict__ a_ws)
{
  __shared__ __align__(16) _Float16 Ah[3][128 * 32];   // 24 KB
  __shared__ __align__(16) _Float16 Bh[3][128 * 32];   // 24 KB

  const int d     = blockIdx.x;
  const int grp   = d >> 3;                 // 0..191
  const int ytile = (d & 7) * 32 + grp / 6; // 0..255
  const int xtile = grp % 6;                // 0..5
  const int r0 = ytile * 128;
  const int c0 = xtile * 128;

  const int tid  = threadIdx.x;
  const int wave = tid >> 6, lane = tid & 63;
  const int wm   = (wave & 1) * 64, wn = (wave >> 1) * 64;
  const int fm   = lane & 15;
  const int fk   = (lane >> 4) * 8;

  float4_t acc[4][4];
#pragma unroll
  for (int i = 0; i < 4; ++i)
#pragma unroll
    for (int j = 0; j < 4; ++j) acc[i][j] = (float4_t)0.0f;

  const int srow = tid >> 2;           // 0..63
  const int scol = (tid & 3) * 8;      // 0,8,16,24

  const unsigned short* pA0 = xh + (size_t)(r0 + srow) * INDIM + scol;
  const unsigned short* pA1 = xh + (size_t)(r0 + 64 + srow) * INDIM + scol;
  const unsigned short* pB0 = wh + (size_t)(c0 + srow) * INDIM + scol;
  const unsigned short* pB1 = wh + (size_t)(c0 + 64 + srow) * INDIM + scol;

  auto stage = [&](int buf, int k0) {
    gload16(pA0 + k0, &Ah[buf][tid * 8]);
    gload16(pA1 + k0, &Ah[buf][(256 + tid) * 8]);
    gload16(pB0 + k0, &Bh[buf][tid * 8]);
    gload16(pB1 + k0, &Bh[buf][(256 + tid) * 8]);
  };

  auto compute = [&](int buf) {
    half8_t a[4], b[4];
#pragma unroll
    for (int i = 0; i < 4; ++i)
      a[i] = *(const half8_t*)&Ah[buf][(wm + i * 16 + fm) * 32 + fk];
#pragma unroll
    for (int j = 0; j < 4; ++j)
      b[j] = *(const half8_t*)&Bh[buf][(wn + j * 16 + fm) * 32 + fk];
    __builtin_amdgcn_s_setprio(1);
#pragma unroll
    for (int i = 0; i < 4; ++i)
#pragma unroll
      for (int j = 0; j < 4; ++j)
        acc[i][j] = __builtin_amdgcn_mfma_f32_16x16x32_f16(a[i], b[j], acc[i][j], 0, 0, 0);
    __builtin_amdgcn_s_setprio(0);
  };

  // depth-2 ring: buffers t%3; stages for t and t+1 always in flight.
  stage(0, 0);
  stage(1, 32);
  int cur = 0;
  for (int t = 0; t < 14; ++t) {
    stage((cur + 2) % 3, (t + 2) * 32);
    asm volatile("s_waitcnt vmcnt(8)" ::: "memory");   // step-t loads done
    __builtin_amdgcn_s_barrier();
    compute(cur);
    __builtin_amdgcn_s_barrier();
    cur = (cur + 1) % 3;
  }
  asm volatile("s_waitcnt vmcnt(4)" ::: "memory");     // step-14 loads done
  __builtin_amdgcn_s_barrier();
  compute(cur);
  cur = (cur + 1) % 3;
  asm volatile("s_waitcnt vmcnt(0)" ::: "memory");     // step-15 loads done
  __builtin_amdgcn_s_barrier();
  compute(cur);

  // epilogue: all four projections written coalesced
#pragma unroll
  for (int j = 0; j < 4; ++j) {
    const int col = c0 + wn + j * 16 + fm;
    if (col >= 704) continue;
    const float bias = bcat[col];
#pragma unroll
    for (int i = 0; i < 4; ++i) {
#pragma unroll
      for (int r = 0; r < 4; ++r) {
        const int row = r0 + wm + i * 16 + (lane >> 4) * 4 + r;  // row = t*4+b
        const float val = acc[i][j][r] + bias;
        if (col < 512) {
          v_ws[(size_t)row * DV + col] = val;
        } else if (col < 576) {
          k_ws[(size_t)row * DK + col - 512] = val;
        } else if (col < 640) {
          q_ws[(size_t)row * DK + col - 576] = val;
        } else {
          a_ws[(size_t)row * DK + col - 640] = 1.0f / (1.0f + expf(-val));
        }
      }
    }
  }
}

// ---------------------------------------------------------------------------
// K2: per-(c,b) chunk prep.  LDS-resident cumprod, then coalesced
// q_t (fp32 q_ws -> Acat hi/lo write) and k_t (k_ws fp32 RMW) passes.
// ---------------------------------------------------------------------------
__global__ __launch_bounds__(256) void prep_kernel(
    const float* __restrict__ a_ws, float* __restrict__ k_ws,
    const float* __restrict__ q_ws,
    unsigned short* __restrict__ Acat_h, unsigned short* __restrict__ Acat_l,
    float* __restrict__ pend)
{
  __shared__ float pal[CHUNK][DK];    // 32 KB: alpha -> cumprod p
  const int c = blockIdx.x, b = blockIdx.y;
  const int cb = c * B_DIM + b;
  const int tid = threadIdx.x;

#pragma unroll
  for (int i = 0; i < 8; ++i) {
    const int f = (i * 256 + tid) * 4;       // 0..8191
    const int t = f >> 6, n0 = f & 63;
    const float4 av = *(const float4*)&a_ws[(size_t)(c * CHUNK + t) * 256 + b * 64 + n0];
    *(float4*)&pal[t][n0] = av;
  }
  __syncthreads();

  if (tid < 64) {
    float p = 1.0f;
#pragma unroll 4
    for (int t = 0; t < CHUNK; ++t) {
      p *= fmaxf(pal[t][tid], EPSF);
      pal[t][tid] = p;
    }
    pend[c * 256 + b * 64 + tid] = p;
  }
  __syncthreads();

#pragma unroll
  for (int i = 0; i < 8; ++i) {
    const int f = (i * 256 + tid) * 4;
    const int t = f >> 6, n0 = f & 63;
    const float4 qv = *(const float4*)&q_ws[(size_t)(c * CHUNK + t) * 256 + b * 64 + n0];
    const size_t qa = ((size_t)cb * CHUNK + t) * KCAT + 128 + n0;
    float q0 = qv.x * pal[t][n0 + 0];
    float q1 = qv.y * pal[t][n0 + 1];
    float q2 = qv.z * pal[t][n0 + 2];
    float q3 = qv.w * pal[t][n0 + 3];
    ushort4 h, l;
    h.x = f2bf(q0); l.x = f2bf(q0 - bf2f(h.x));
    h.y = f2bf(q1); l.y = f2bf(q1 - bf2f(h.y));
    h.z = f2bf(q2); l.z = f2bf(q2 - bf2f(h.z));
    h.w = f2bf(q3); l.w = f2bf(q3 - bf2f(h.w));
    *(ushort4*)&Acat_h[qa] = h;
    *(ushort4*)&Acat_l[qa] = l;
  }

#pragma unroll
  for (int i = 0; i < 8; ++i) {
    const int f = (i * 256 + tid) * 4;
    const int t = f >> 6, n0 = f & 63;
    const size_t ka = (size_t)(c * CHUNK + t) * 256 + b * 64 + n0;
    float4 kv = *(const float4*)&k_ws[ka];
    kv.x = kv.x / (pal[t][n0 + 0] + EPSF);
    kv.y = kv.y / (pal[t][n0 + 1] + EPSF);
    kv.z = kv.z / (pal[t][n0 + 2] + EPSF);
    kv.w = kv.w / (pal[t][n0 + 3] + EPSF);
    *(float4*)&k_ws[ka] = kv;
  }
}

// ---------------------------------------------------------------------------
// K4b: transpose-cast v -> Bt hi/lo, layout [(c,b)][d][s] bf16.
// ---------------------------------------------------------------------------
__global__ __launch_bounds__(256) void vt_kernel(
    const float* __restrict__ v_ws,
    unsigned short* __restrict__ Bt_h, unsigned short* __restrict__ Bt_l)
{
  __shared__ float Ts[CHUNK][65];
  const int c = blockIdx.x, b = blockIdx.y, dblk = blockIdx.z;
  const int cb = c * B_DIM + b;
  const int d0 = dblk * 64;
  const int tid = threadIdx.x;
#pragma unroll
  for (int q = 0; q < 8; ++q) {
    const int idx = (q * 256 + tid) * 4;       // 0..8191
    const int s = idx >> 6, dd = idx & 63;
    const float4 v = *(const float4*)&v_ws[(size_t)((c * CHUNK + s) * B_DIM + b) * DV + d0 + dd];
    Ts[s][dd + 0] = v.x; Ts[s][dd + 1] = v.y;
    Ts[s][dd + 2] = v.z; Ts[s][dd + 3] = v.w;
  }
  __syncthreads();
#pragma unroll
  for (int q = 0; q < 8; ++q) {
    const int idx = (q * 256 + tid) * 4;
    const int dd = idx >> 7, s0 = idx & 127;
    float v0 = Ts[s0 + 0][dd], v1 = Ts[s0 + 1][dd];
    float v2 = Ts[s0 + 2][dd], v3 = Ts[s0 + 3][dd];
    ushort4 h, l;
    h.x = f2bf(v0); l.x = f2bf(v0 - bf2f(h.x));
    h.y = f2bf(v1); l.y = f2bf(v1 - bf2f(h.y));
    h.z = f2bf(v2); l.z = f2bf(v2 - bf2f(h.z));
    h.w = f2bf(v3); l.w = f2bf(v3 - bf2f(h.w));
    const size_t oa = ((size_t)cb * DV + d0 + dd) * CHUNK + s0;
    *(ushort4*)&Bt_h[oa] = h;
    *(ushort4*)&Bt_l[oa] = l;
  }
}

// ---------------------------------------------------------------------------
// K3: wchunk via MFMA.  W[d][n] = (sum_t v^T[d][t]*k_t[t][n]) * pend[n].
// ---------------------------------------------------------------------------
__global__ __launch_bounds__(256) void wchunk_mfma_kernel(
    const unsigned short* __restrict__ Bt_h, const unsigned short* __restrict__ Bt_l,
    const float* __restrict__ k_ws, const float* __restrict__ pend,
    float* __restrict__ W_ws)
{
  __shared__ __align__(16) unsigned short Ah[128 * 32];
  __shared__ __align__(16) unsigned short Al[128 * 32];

  const int c = blockIdx.x, b = blockIdx.y, dt = blockIdx.z;
  const int cb = c * B_DIM + b;
  const int tid  = threadIdx.x;
  const int wave = tid >> 6, lane = tid & 63;
  const int wm   = (wave & 1) * 64;
  const int wn   = (wave >> 1) * 32;
  const int fm   = lane & 15;
  const int fk   = (lane >> 4) * 8;

  const unsigned short* Ab_h = Bt_h + ((size_t)cb * DV + dt * 128) * CHUNK;
  const unsigned short* Ab_l = Bt_l + ((size_t)cb * DV + dt * 128) * CHUNK;

  float4_t acc[4][2];
#pragma unroll
  for (int i = 0; i < 4; ++i)
#pragma unroll
    for (int j = 0; j < 2; ++j) acc[i][j] = (float4_t)0.0f;

  for (int ks = 0; ks < 4; ++ks) {
    const int k0 = ks * 32;
#pragma unroll
    for (int q = 0; q < 2; ++q) {
      const int flat = (q * 256 + tid) * 8;
      const int row = flat >> 5, col = flat & 31;
      gload16(&Ab_h[(size_t)row * CHUNK + k0 + col], &Ah[flat]);
      gload16(&Ab_l[(size_t)row * CHUNK + k0 + col], &Al[flat]);
    }

    short8_t b_hi[2], b_lo[2];
#pragma unroll
    for (int j = 0; j < 2; ++j) {
      const int n = wn + j * 16 + fm;
#pragma unroll
      for (int e = 0; e < 8; ++e) {
        const float kv = k_ws[(size_t)(c * CHUNK + k0 + fk + e) * 256 + b * 64 + n];
        const unsigned short h = f2bf(kv);
        b_hi[j][e] = (short)h;
        b_lo[j][e] = (short)f2bf(kv - bf2f(h));
      }
    }
    __syncthreads();

    short8_t a_hi[4], a_lo[4];
#pragma unroll
    for (int i = 0; i < 4; ++i) {
      const int ar = (wm + i * 16 + fm) * 32 + fk;
      a_hi[i] = *(const short8_t*)&Ah[ar];
      a_lo[i] = *(const short8_t*)&Al[ar];
    }
#pragma unroll
    for (int i = 0; i < 4; ++i)
#pragma unroll
      for (int j = 0; j < 2; ++j) {
        acc[i][j] = __builtin_amdgcn_mfma_f32_16x16x32_bf16(a_hi[i], b_hi[j], acc[i][j], 0, 0, 0);
        acc[i][j] = __builtin_amdgcn_mfma_f32_16x16x32_bf16(a_lo[i], b_hi[j], acc[i][j], 0, 0, 0);
        acc[i][j] = __builtin_amdgcn_mfma_f32_16x16x32_bf16(a_hi[i], b_lo[j], acc[i][j], 0, 0, 0);
      }
    __syncthreads();
  }

#pragma unroll
  for (int j = 0; j < 2; ++j) {
    const int n = wn + j * 16 + fm;
    const float pj = pend[c * 256 + b * 64 + n];
#pragma unroll
    for (int i = 0; i < 4; ++i) {
#pragma unroll
      for (int r = 0; r < 4; ++r) {
        const int d = dt * 128 + wm + i * 16 + (lane >> 4) * 4 + r;
        W_ws[((size_t)cb * DV + d) * DK + n] = acc[i][j][r] * pj;
      }
    }
  }
}

// ---------------------------------------------------------------------------
// K4: sequential state scan over chunks.  W_ws read-only; the pre-update
// state S_c is emitted directly as split-bf16 (Sh/Sl) for out_mfma's
// uniform global_load_lds staging.  Bit-identical to the old in-out convert.
// ---------------------------------------------------------------------------
__global__ __launch_bounds__(256) void scan_kernel(
    const float* __restrict__ W_ws, const float* __restrict__ pend,
    unsigned short* __restrict__ Sh, unsigned short* __restrict__ Sl)
{
  const int flat = blockIdx.x * 256 + threadIdx.x;
  const int n = flat & 63;
  const int bd = flat >> 6;
  const int b = bd >> 9;
  float s = 0.0f;
  for (int c = 0; c < NCH; ++c) {
    const int off = c * 131072 + flat;
    const float w = W_ws[off];
    const unsigned short h = f2bf(s);
    Sh[off] = h;
    Sl[off] = f2bf(s - bf2f(h));
    s = s * pend[c * 256 + b * 64 + n] + w;
  }
}

// ---------------------------------------------------------------------------
// K5: A = tril(q_t @ k_t^T) via MFMA.  Single K=64 step with [128][64]
// XOR-swizzled tiles (one barrier instead of four).
// ---------------------------------------------------------------------------
__global__ __launch_bounds__(256) void score_mfma_kernel(
    const float* __restrict__ k_ws,
    unsigned short* __restrict__ Acat_h, unsigned short* __restrict__ Acat_l)
{
  __shared__ __align__(16) unsigned short Ah[128 * 64];
  __shared__ __align__(16) unsigned short Al[128 * 64];
  __shared__ __align__(16) unsigned short Bh[128 * 64];
  __shared__ __align__(16) unsigned short Bl[128 * 64];

  const int c = blockIdx.x, b = blockIdx.y;
  const int cb = c * B_DIM + b;
  const int tid  = threadIdx.x;
  const int wave = tid >> 6, lane = tid & 63;
  const int wm   = (wave & 1) * 64, wn = (wave >> 1) * 64;
  const int fm   = lane & 15;
  const int fk   = (lane >> 4) * 8;

  const unsigned short* Aq_h = Acat_h + (size_t)cb * CHUNK * KCAT + 128;
  const unsigned short* Aq_l = Acat_l + (size_t)cb * CHUNK * KCAT + 128;

  // A stage: [128][64] tile via gload16, source pre-swizzled (LDS dest is
  // linear lane*16B per wave; source global addr carries the swizzle).
  const int srow = tid >> 3;          // 0..31
  const int scolB = (tid & 7) * 16;   // byte col
  const int sc = (scolB ^ ((srow & 7) << 4)) >> 1;   // halfs
  const int sdst = srow * 64 + (scolB >> 1);
#pragma unroll
  for (int q = 0; q < 4; ++q) {
    const int row = q * 32 + srow;
    const int dst = q * 2048 + sdst;
    gload16(&Aq_h[(size_t)row * KCAT + sc], &Ah[dst]);
    gload16(&Aq_l[(size_t)row * KCAT + sc], &Al[dst]);
  }
  // B stage: k_t fp32 -> split bf16, swizzled ds_write.
#pragma unroll
  for (int q = 0; q < 8; ++q) {
    const int f = (q * 256 + tid) * 4;
    const int s = f >> 6, n0 = f & 63;
    const float4 kv = *(const float4*)&k_ws[(size_t)(c * CHUNK + s) * 256 + b * 64 + n0];
    ushort4 h, l;
    h.x = f2bf(kv.x); l.x = f2bf(kv.x - bf2f(h.x));
    h.y = f2bf(kv.y); l.y = f2bf(kv.y - bf2f(h.y));
    h.z = f2bf(kv.z); l.z = f2bf(kv.z - bf2f(h.z));
    h.w = f2bf(kv.w); l.w = f2bf(kv.w - bf2f(h.w));
    const int wi = s * 64 + (n0 ^ ((s & 7) << 3));
    *(ushort4*)&Bh[wi] = h;
    *(ushort4*)&Bl[wi] = l;
  }
  __syncthreads();

  float4_t acc[4][4];
#pragma unroll
  for (int i = 0; i < 4; ++i)
#pragma unroll
    for (int j = 0; j < 4; ++j) acc[i][j] = (float4_t)0.0f;

#pragma unroll
  for (int ksub = 0; ksub < 2; ++ksub) {
    short8_t a_hi[4], a_lo[4], b_hi[4], b_lo[4];
#pragma unroll
    for (int i = 0; i < 4; ++i) {
      const int r = wm + i * 16 + fm;
      const int ar = r * 64 + ((ksub * 32 + fk) ^ ((r & 7) << 3));
      a_hi[i] = *(const short8_t*)&Ah[ar];
      a_lo[i] = *(const short8_t*)&Al[ar];
    }
#pragma unroll
    for (int j = 0; j < 4; ++j) {
      const int r = wn + j * 16 + fm;
      const int br = r * 64 + ((ksub * 32 + fk) ^ ((r & 7) << 3));
      b_hi[j] = *(const short8_t*)&Bh[br];
      b_lo[j] = *(const short8_t*)&Bl[br];
    }
    __builtin_amdgcn_s_setprio(1);
#pragma unroll
    for (int i = 0; i < 4; ++i)
#pragma unroll
      for (int j = 0; j < 4; ++j) {
        acc[i][j] = __builtin_amdgcn_mfma_f32_16x16x32_bf16(a_hi[i], b_hi[j], acc[i][j], 0, 0, 0);
        acc[i][j] = __builtin_amdgcn_mfma_f32_16x16x32_bf16(a_lo[i], b_hi[j], acc[i][j], 0, 0, 0);
        acc[i][j] = __builtin_amdgcn_mfma_f32_16x16x32_bf16(a_hi[i], b_lo[j], acc[i][j], 0, 0, 0);
      }
    __builtin_amdgcn_s_setprio(0);
  }

#pragma unroll
  for (int j = 0; j < 4; ++j) {
    const int s = wn + j * 16 + fm;
#pragma unroll
    for (int i = 0; i < 4; ++i) {
#pragma unroll
      for (int r = 0; r < 4; ++r) {
        const int t = wm + i * 16 + (lane >> 4) * 4 + r;
        const float vv = (s <= t) ? acc[i][j][r] : 0.0f;
        const unsigned short h = f2bf(vv);
        const size_t oa = ((size_t)cb * CHUNK + t) * KCAT + s;
        Acat_h[oa] = h;
        Acat_l[oa] = f2bf(vv - bf2f(h));
      }
    }
  }
}

// ---------------------------------------------------------------------------
// K6: y = [A|q_t] @ [v ; S^T].  3 uniform K=64 steps with [128][64]
// XOR-swizzled tiles, all staged via global_load_lds (S pre-split by scan).
// ---------------------------------------------------------------------------
__global__ __launch_bounds__(256) void out_mfma_kernel(
    const unsigned short* __restrict__ Acat_h, const unsigned short* __restrict__ Acat_l,
    const unsigned short* __restrict__ Bt_h, const unsigned short* __restrict__ Bt_l,
    const unsigned short* __restrict__ Sh, const unsigned short* __restrict__ Sl,
    float* __restrict__ out)
{
  __shared__ __align__(16) unsigned short Ah[128 * 64];
  __shared__ __align__(16) unsigned short Al[128 * 64];
  __shared__ __align__(16) unsigned short Bh[128 * 64];
  __shared__ __align__(16) unsigned short Bl[128 * 64];

  const int c = blockIdx.x, b = blockIdx.y, nt = blockIdx.z;
  const int cb = c * B_DIM + b;
  const int tid  = threadIdx.x;
  const int wave = tid >> 6, lane = tid & 63;
  const int wm   = (wave & 1) * 64, wn = (wave >> 1) * 64;
  const int fm   = lane & 15;
  const int fk   = (lane >> 4) * 8;

  const unsigned short* Ab_h = Acat_h + (size_t)cb * CHUNK * KCAT;
  const unsigned short* Ab_l = Acat_l + (size_t)cb * CHUNK * KCAT;
  const unsigned short* Bb_h = Bt_h + ((size_t)cb * DV + nt * 128) * CHUNK;
  const unsigned short* Bb_l = Bt_l + ((size_t)cb * DV + nt * 128) * CHUNK;
  const unsigned short* Sb_h = Sh + ((size_t)cb * DV + nt * 128) * DK;
  const unsigned short* Sb_l = Sl + ((size_t)cb * DV + nt * 128) * DK;

  const int srow = tid >> 3;          // 0..31
  const int scolB = (tid & 7) * 16;
  const int sc = (scolB ^ ((srow & 7) << 4)) >> 1;   // halfs
  const int sdst = srow * 64 + (scolB >> 1);

  float4_t acc[4][4];
#pragma unroll
  for (int i = 0; i < 4; ++i)
#pragma unroll
    for (int j = 0; j < 4; ++j) acc[i][j] = (float4_t)0.0f;

  for (int ks = 0; ks < 3; ++ks) {
    const int k0 = ks * 64;
#pragma unroll
    for (int q = 0; q < 4; ++q) {
      const int row = q * 32 + srow;
      const int dst = q * 2048 + sdst;
      gload16(&Ab_h[(size_t)row * KCAT + k0 + sc], &Ah[dst]);
      gload16(&Ab_l[(size_t)row * KCAT + k0 + sc], &Al[dst]);
      if (ks < 2) {
        gload16(&Bb_h[(size_t)row * CHUNK + k0 + sc], &Bh[dst]);
        gload16(&Bb_l[(size_t)row * CHUNK + k0 + sc], &Bl[dst]);
      } else {
        gload16(&Sb_h[(size_t)row * DK + sc], &Bh[dst]);
        gload16(&Sb_l[(size_t)row * DK + sc], &Bl[dst]);
      }
    }
    __syncthreads();

#pragma unroll
    for (int ksub = 0; ksub < 2; ++ksub) {
      short8_t a_hi[4], a_lo[4], b_hi[4], b_lo[4];
#pragma unroll
      for (int i = 0; i < 4; ++i) {
        const int r = wm + i * 16 + fm;
        const int ar = r * 64 + ((ksub * 32 + fk) ^ ((r & 7) << 3));
        a_hi[i] = *(const short8_t*)&Ah[ar];
        a_lo[i] = *(const short8_t*)&Al[ar];
      }
#pragma unroll
      for (int j = 0; j < 4; ++j) {
        const int r = wn + j * 16 + fm;
        const int br = r * 64 + ((ksub * 32 + fk) ^ ((r & 7) << 3));
        b_hi[j] = *(const short8_t*)&Bh[br];
        b_lo[j] = *(const short8_t*)&Bl[br];
      }
      __builtin_amdgcn_s_setprio(1);
#pragma unroll
      for (int i = 0; i < 4; ++i)
#pragma unroll
        for (int j = 0; j < 4; ++j) {
          acc[i][j] = __builtin_amdgcn_mfma_f32_16x16x32_bf16(a_hi[i], b_hi[j], acc[i][j], 0, 0, 0);
          acc[i][j] = __builtin_amdgcn_mfma_f32_16x16x32_bf16(a_lo[i], b_hi[j], acc[i][j], 0, 0, 0);
          acc[i][j] = __builtin_amdgcn_mfma_f32_16x16x32_bf16(a_hi[i], b_lo[j], acc[i][j], 0, 0, 0);
        }
      __builtin_amdgcn_s_setprio(0);
    }
    __syncthreads();
  }

#pragma unroll
  for (int j = 0; j < 4; ++j) {
    const int d = nt * 128 + wn + j * 16 + fm;
#pragma unroll
    for (int i = 0; i < 4; ++i) {
#pragma unroll
      for (int r = 0; r < 4; ++r) {
        const int t = c * CHUNK + wm + i * 16 + (lane >> 4) * 4 + r;
        out[((size_t)t * B_DIM + b) * DV + d] = acc[i][j][r];
      }
    }
  }
}

// ---------------------------------------------------------------------------
extern "C" void kernel_launch(void* const* d_in, const int* in_sizes, int n_in,
                              void* d_out, int out_size, void* d_ws, size_t ws_size,
                              hipStream_t stream)
{
  const float* x  = (const float*)d_in[0];
  const float* Wv = (const float*)d_in[1];
  const float* bv = (const float*)d_in[2];
  const float* Wk = (const float*)d_in[3];
  const float* bk = (const float*)d_in[4];
  const float* Wq = (const float*)d_in[5];
  const float* bq = (const float*)d_in[6];
  const float* Wa = (const float*)d_in[7];
  const float* ba = (const float*)d_in[8];
  float* out = (float*)d_out;

  // ---- workspace layout (unchanged footprint) ----
  float* ws   = (float*)d_ws;
  float* v_ws = ws;                                         // 16,777,216 f
  float* k_ws = v_ws + (size_t)ROWS * DV;                   //  2,097,152 f
  float* a_ws = k_ws + (size_t)ROWS * DK;                   //  2,097,152 f
  float* pend = a_ws + (size_t)ROWS * DK;                   //     16,384 f
  float* W_ws = pend + NCH * B_DIM * DK;                    //  8,388,608 f
  float* bcat = W_ws + (size_t)NCH * B_DIM * DV * DK;       //        768 f
  unsigned short* Acat_h = (unsigned short*)(bcat + NPAD);  //  6,291,456 us
  unsigned short* Acat_l = Acat_h + (size_t)NCH * B_DIM * CHUNK * KCAT;
  unsigned short* uni = Acat_l + (size_t)NCH * B_DIM * CHUNK * KCAT;
  // union A: fp16 proj staging (dead after proj_mfma)
  unsigned short* xh = uni;                                 // 16,777,216 us
  unsigned short* wh = xh + (size_t)ROWS * INDIM;           //    393,216 us
  // q_ws: fp32 q staging (consumed by prep BEFORE vt writes Bt).
  float* q_ws = (float*)(uni + (size_t)18 * 1024 * 1024);   //  2,097,152 f
  // union B: v^T split-bf16 (written by vt_kernel after prep) — 64 MiB
  unsigned short* Bt_h = uni;
  unsigned short* Bt_l = Bt_h + (size_t)NCH * B_DIM * DV * CHUNK;
  // Sh/Sl: split-bf16 state, aliased over v_ws (dead after vt_kernel).
  unsigned short* S_h = (unsigned short*)v_ws;              //  8,388,608 us
  unsigned short* S_l = S_h + (size_t)NCH * B_DIM * DV * DK;

  cast_kernel<<<16384 + 384, 256, 0, stream>>>(
      x, Wv, Wk, Wq, Wa, bv, bk, bq, ba, xh, wh, bcat);
  proj_mfma_kernel<<<(ROWS / 128) * (NPAD / 128), 256, 0, stream>>>(
      xh, wh, bcat, v_ws, k_ws, q_ws, a_ws);
  prep_kernel<<<dim3(NCH, B_DIM), 256, 0, stream>>>(
      a_ws, k_ws, q_ws, Acat_h, Acat_l, pend);
  vt_kernel<<<dim3(NCH, B_DIM, 8), 256, 0, stream>>>(v_ws, Bt_h, Bt_l);
  wchunk_mfma_kernel<<<dim3(NCH, B_DIM, 4), 256, 0, stream>>>(
      Bt_h, Bt_l, k_ws, pend, W_ws);
  scan_kernel<<<(B_DIM * DV * DK) / 256, 256, 0, stream>>>(
      W_ws, pend, S_h, S_l);
  score_mfma_kernel<<<dim3(NCH, B_DIM), 256, 0, stream>>>(
      k_ws, Acat_h, Acat_l);
  out_mfma_kernel<<<dim3(NCH, B_DIM, 4), 256, 0, stream>>>(
      Acat_h, Acat_l, Bt_h, Bt_l, S_h, S_l, out);
}

// Round 4
// 269.865 us; speedup vs baseline: 1.2249x; 1.1266x over previous
//
#include <hip/hip_runtime.h>
#include <math.h>

#define T_DIM 8192
#define B_DIM 4
#define INDIM 512
#define DV 512
#define DK 64
#define CHUNK 128
#define NCH (T_DIM / CHUNK)     // 64
#define ROWS (T_DIM * B_DIM)    // 32768
#define NPAD 768                // 704 proj cols padded to 6x128
#define KCAT 192                // 128 intra + 64 state
#define EPSF 1e-8f

typedef float float4_t __attribute__((ext_vector_type(4)));
typedef short short8_t __attribute__((ext_vector_type(8)));
typedef _Float16 half8_t __attribute__((ext_vector_type(8)));

__device__ inline unsigned short f2bf(float f) {
  unsigned int u = __float_as_uint(f);
  unsigned int r = (u + 0x7fffu + ((u >> 16) & 1u)) >> 16;
  return (unsigned short)r;
}
__device__ inline float bf2f(unsigned short h) {
  return __uint_as_float(((unsigned int)h) << 16);
}
__device__ inline unsigned short f2h(float f) {
  _Float16 h = (_Float16)f;
  unsigned short u;
  __builtin_memcpy(&u, &h, 2);
  return u;
}

__device__ inline void gload16(const void* g, void* l) {
  __builtin_amdgcn_global_load_lds(
      (const __attribute__((address_space(1))) void*)g,
      (__attribute__((address_space(3))) void*)l, 16, 0, 0);
}

// ---------------------------------------------------------------------------
// C0: merged fp16 cast.  blocks [0,16384): x -> xh (fp16).
// blocks [16384,16768): padded concat weights -> wh (fp16) + bcat.
// ---------------------------------------------------------------------------
__global__ __launch_bounds__(256) void cast_kernel(
    const float* __restrict__ x,
    const float* __restrict__ Wv, const float* __restrict__ Wk,
    const float* __restrict__ Wq, const float* __restrict__ Wa,
    const float* __restrict__ bv, const float* __restrict__ bk,
    const float* __restrict__ bq, const float* __restrict__ ba,
    unsigned short* __restrict__ xh, unsigned short* __restrict__ wh,
    float* __restrict__ bcat)
{
  if (blockIdx.x < 16384) {
    const size_t i4 = ((size_t)blockIdx.x * 256 + threadIdx.x) * 4;
    const float4 v = *(const float4*)&x[i4];
    ushort4 h;
    h.x = f2h(v.x); h.y = f2h(v.y); h.z = f2h(v.z); h.w = f2h(v.w);
    *(ushort4*)&xh[i4] = h;
  } else {
    const int t = (blockIdx.x - 16384) * 256 + threadIdx.x;
    const size_t i4 = (size_t)t * 4;
    const int row = (int)(i4 >> 9);
    const int col = (int)(i4 & 511);
    float4 v = {0.f, 0.f, 0.f, 0.f};
    if (row < 512)      v = *(const float4*)&Wv[(size_t)row * INDIM + col];
    else if (row < 576) v = *(const float4*)&Wk[(size_t)(row - 512) * INDIM + col];
    else if (row < 640) v = *(const float4*)&Wq[(size_t)(row - 576) * INDIM + col];
    else if (row < 704) v = *(const float4*)&Wa[(size_t)(row - 640) * INDIM + col];
    ushort4 h;
    h.x = f2h(v.x); h.y = f2h(v.y); h.z = f2h(v.z); h.w = f2h(v.w);
    *(ushort4*)&wh[i4] = h;
    if (t < NPAD) {
      float b = 0.f;
      if (t < 512)      b = bv[t];
      else if (t < 576) b = bk[t - 512];
      else if (t < 640) b = bq[t - 576];
      else if (t < 704) b = ba[t - 640];
      bcat[t] = b;
    }
  }
}

// ---------------------------------------------------------------------------
// K1: fp16 MFMA projection GEMM (M=32768,K=512,N=768), fp32 accumulate.
// Round-8: v-columns (xtile<4) are transposed in-LDS and written DIRECTLY as
// split-bf16 Bt[(cb)][d][s] — vt_kernel eliminated (-128 MB traffic).
// Key fact: acc[i][j][r]'s 4 r-values are the 4 batch lanes of one (t,d).
// ---------------------------------------------------------------------------
__global__ __launch_bounds__(256) void proj_mfma_kernel(
    const unsigned short* __restrict__ xh, const unsigned short* __restrict__ wh,
    const float* __restrict__ bcat,
    unsigned short* __restrict__ Bt_h, unsigned short* __restrict__ Bt_l,
    float* __restrict__ k_ws, float* __restrict__ q_ws,
    float* __restrict__ a_ws)
{
  __shared__ __align__(16) _Float16 Ah[3][128 * 32];   // 24 KB
  __shared__ __align__(16) _Float16 Bh[3][128 * 32];   // 24 KB

  const int d     = blockIdx.x;
  const int grp   = d >> 3;                 // 0..191
  const int ytile = (d & 7) * 32 + grp / 6; // 0..255
  const int xtile = grp % 6;                // 0..5
  const int r0 = ytile * 128;
  const int c0 = xtile * 128;

  const int tid  = threadIdx.x;
  const int wave = tid >> 6, lane = tid & 63;
  const int wm   = (wave & 1) * 64, wn = (wave >> 1) * 64;
  const int fm   = lane & 15;
  const int fk   = (lane >> 4) * 8;
  const int g    = lane >> 4;

  float4_t acc[4][4];
#pragma unroll
  for (int i = 0; i < 4; ++i)
#pragma unroll
    for (int j = 0; j < 4; ++j) acc[i][j] = (float4_t)0.0f;

  const int srow = tid >> 2;           // 0..63
  const int scol = (tid & 3) * 8;      // 0,8,16,24

  const unsigned short* pA0 = xh + (size_t)(r0 + srow) * INDIM + scol;
  const unsigned short* pA1 = xh + (size_t)(r0 + 64 + srow) * INDIM + scol;
  const unsigned short* pB0 = wh + (size_t)(c0 + srow) * INDIM + scol;
  const unsigned short* pB1 = wh + (size_t)(c0 + 64 + srow) * INDIM + scol;

  auto stage = [&](int buf, int k0) {
    gload16(pA0 + k0, &Ah[buf][tid * 8]);
    gload16(pA1 + k0, &Ah[buf][(256 + tid) * 8]);
    gload16(pB0 + k0, &Bh[buf][tid * 8]);
    gload16(pB1 + k0, &Bh[buf][(256 + tid) * 8]);
  };

  auto compute = [&](int buf) {
    half8_t a[4], b[4];
#pragma unroll
    for (int i = 0; i < 4; ++i)
      a[i] = *(const half8_t*)&Ah[buf][(wm + i * 16 + fm) * 32 + fk];
#pragma unroll
    for (int j = 0; j < 4; ++j)
      b[j] = *(const half8_t*)&Bh[buf][(wn + j * 16 + fm) * 32 + fk];
    __builtin_amdgcn_s_setprio(1);
#pragma unroll
    for (int i = 0; i < 4; ++i)
#pragma unroll
      for (int j = 0; j < 4; ++j)
        acc[i][j] = __builtin_amdgcn_mfma_f32_16x16x32_f16(a[i], b[j], acc[i][j], 0, 0, 0);
    __builtin_amdgcn_s_setprio(0);
  };

  // depth-2 ring: buffers t%3; stages for t and t+1 always in flight.
  stage(0, 0);
  stage(1, 32);
  int cur = 0;
  for (int t = 0; t < 14; ++t) {
    stage((cur + 2) % 3, (t + 2) * 32);
    asm volatile("s_waitcnt vmcnt(8)" ::: "memory");   // step-t loads done
    __builtin_amdgcn_s_barrier();
    compute(cur);
    __builtin_amdgcn_s_barrier();
    cur = (cur + 1) % 3;
  }
  asm volatile("s_waitcnt vmcnt(4)" ::: "memory");     // step-14 loads done
  __builtin_amdgcn_s_barrier();
  compute(cur);
  cur = (cur + 1) % 3;
  asm volatile("s_waitcnt vmcnt(0)" ::: "memory");     // step-15 loads done
  __builtin_amdgcn_s_barrier();
  compute(cur);

  if (xtile < 4) {
    // ---- v path: LDS transpose -> Bt split-bf16 ----
    // Block rows r0..r0+127 = t in [t0, t0+32) x b in [0,4); cols = d range.
    unsigned int* Thl = (unsigned int*)&Ah[0][0];   // 17.4 KB of 24 KB
    const int t0 = r0 >> 2;            // multiple of 32
    const int cb0 = (t0 >> 7) * 4;     // chunk*4
    const int s0 = t0 & 127;           // s offset within chunk (0/32/64/96)
    __syncthreads();                   // protect Ah from last compute reads
    for (int bb = 0; bb < 4; ++bb) {
#pragma unroll
      for (int j = 0; j < 4; ++j) {
        const int d_loc = wn + j * 16 + fm;
        const float bias = bcat[c0 + d_loc];
#pragma unroll
        for (int i = 0; i < 4; ++i) {
          const int trow = (wm >> 2) + i * 4 + g;       // 0..31
          const float val = acc[i][j][bb] + bias;
          const unsigned short h = f2bf(val);
          const unsigned short l = f2bf(val - bf2f(h));
          Thl[d_loc * 34 + trow] = (unsigned int)h | ((unsigned int)l << 16);
        }
      }
      __syncthreads();
#pragma unroll
      for (int q2 = 0; q2 < 4; ++q2) {
        const int task = q2 * 256 + tid;   // 0..1023
        const int dd = task >> 3;          // 0..127
        const int tq = task & 7;           // 0..7
        const unsigned int* p = &Thl[dd * 34 + tq * 4];
        const unsigned int w0 = p[0], w1 = p[1], w2 = p[2], w3 = p[3];
        ushort4 hh, ll;
        hh.x = (unsigned short)w0; ll.x = (unsigned short)(w0 >> 16);
        hh.y = (unsigned short)w1; ll.y = (unsigned short)(w1 >> 16);
        hh.z = (unsigned short)w2; ll.z = (unsigned short)(w2 >> 16);
        hh.w = (unsigned short)w3; ll.w = (unsigned short)(w3 >> 16);
        const size_t oa = ((size_t)(cb0 + bb) * DV + c0 + dd) * CHUNK + s0 + tq * 4;
        *(ushort4*)&Bt_h[oa] = hh;
        *(ushort4*)&Bt_l[oa] = ll;
      }
      __syncthreads();
    }
  } else {
    // ---- k/q/a path: coalesced fp32 stores ----
#pragma unroll
    for (int j = 0; j < 4; ++j) {
      const int col = c0 + wn + j * 16 + fm;
      if (col >= 704) continue;
      const float bias = bcat[col];
#pragma unroll
      for (int i = 0; i < 4; ++i) {
#pragma unroll
        for (int r = 0; r < 4; ++r) {
          const int row = r0 + wm + i * 16 + g * 4 + r;  // row = t*4+b
          const float val = acc[i][j][r] + bias;
          if (col < 576) {
            k_ws[(size_t)row * DK + col - 512] = val;
          } else if (col < 640) {
            q_ws[(size_t)row * DK + col - 576] = val;
          } else {
            a_ws[(size_t)row * DK + col - 640] = 1.0f / (1.0f + expf(-val));
          }
        }
      }
    }
  }
}

// ---------------------------------------------------------------------------
// K2: per-(c,b) chunk prep (512 threads for latency hiding).  LDS cumprod,
// then coalesced q_t (fp32 -> Acat hi/lo) and k_t (fp32 RMW) passes.
// ---------------------------------------------------------------------------
__global__ __launch_bounds__(512) void prep_kernel(
    const float* __restrict__ a_ws, float* __restrict__ k_ws,
    const float* __restrict__ q_ws,
    unsigned short* __restrict__ Acat_h, unsigned short* __restrict__ Acat_l,
    float* __restrict__ pend)
{
  __shared__ float pal[CHUNK][DK];    // 32 KB: alpha -> cumprod p
  const int c = blockIdx.x, b = blockIdx.y;
  const int cb = c * B_DIM + b;
  const int tid = threadIdx.x;

#pragma unroll
  for (int i = 0; i < 4; ++i) {
    const int f = (i * 512 + tid) * 4;       // 0..8191
    const int t = f >> 6, n0 = f & 63;
    const float4 av = *(const float4*)&a_ws[(size_t)(c * CHUNK + t) * 256 + b * 64 + n0];
    *(float4*)&pal[t][n0] = av;
  }
  __syncthreads();

  if (tid < 64) {
    float p = 1.0f;
#pragma unroll 4
    for (int t = 0; t < CHUNK; ++t) {
      p *= fmaxf(pal[t][tid], EPSF);
      pal[t][tid] = p;
    }
    pend[c * 256 + b * 64 + tid] = p;
  }
  __syncthreads();

#pragma unroll
  for (int i = 0; i < 4; ++i) {
    const int f = (i * 512 + tid) * 4;
    const int t = f >> 6, n0 = f & 63;
    const float4 qv = *(const float4*)&q_ws[(size_t)(c * CHUNK + t) * 256 + b * 64 + n0];
    const size_t qa = ((size_t)cb * CHUNK + t) * KCAT + 128 + n0;
    float q0 = qv.x * pal[t][n0 + 0];
    float q1 = qv.y * pal[t][n0 + 1];
    float q2 = qv.z * pal[t][n0 + 2];
    float q3 = qv.w * pal[t][n0 + 3];
    ushort4 h, l;
    h.x = f2bf(q0); l.x = f2bf(q0 - bf2f(h.x));
    h.y = f2bf(q1); l.y = f2bf(q1 - bf2f(h.y));
    h.z = f2bf(q2); l.z = f2bf(q2 - bf2f(h.z));
    h.w = f2bf(q3); l.w = f2bf(q3 - bf2f(h.w));
    *(ushort4*)&Acat_h[qa] = h;
    *(ushort4*)&Acat_l[qa] = l;
  }

#pragma unroll
  for (int i = 0; i < 4; ++i) {
    const int f = (i * 512 + tid) * 4;
    const int t = f >> 6, n0 = f & 63;
    const size_t ka = (size_t)(c * CHUNK + t) * 256 + b * 64 + n0;
    float4 kv = *(const float4*)&k_ws[ka];
    kv.x = kv.x / (pal[t][n0 + 0] + EPSF);
    kv.y = kv.y / (pal[t][n0 + 1] + EPSF);
    kv.z = kv.z / (pal[t][n0 + 2] + EPSF);
    kv.w = kv.w / (pal[t][n0 + 3] + EPSF);
    *(float4*)&k_ws[ka] = kv;
  }
}

// ---------------------------------------------------------------------------
// K3: wchunk via MFMA.  W[d][n] = (sum_t v^T[d][t]*k_t[t][n]) * pend[n].
// 1D grid, XCD-grouped so the 4 dt-blocks of one (c,b) share an XCD's L2.
// ---------------------------------------------------------------------------
__global__ __launch_bounds__(256) void wchunk_mfma_kernel(
    const unsigned short* __restrict__ Bt_h, const unsigned short* __restrict__ Bt_l,
    const float* __restrict__ k_ws, const float* __restrict__ pend,
    float* __restrict__ W_ws)
{
  __shared__ __align__(16) unsigned short Ah[128 * 32];
  __shared__ __align__(16) unsigned short Al[128 * 32];

  const int bd = blockIdx.x;
  const int cb = (bd >> 5) * 8 + (bd & 7);
  const int dt = (bd >> 3) & 3;
  const int c = cb >> 2, b = cb & 3;
  const int tid  = threadIdx.x;
  const int wave = tid >> 6, lane = tid & 63;
  const int wm   = (wave & 1) * 64;
  const int wn   = (wave >> 1) * 32;
  const int fm   = lane & 15;
  const int fk   = (lane >> 4) * 8;

  const unsigned short* Ab_h = Bt_h + ((size_t)cb * DV + dt * 128) * CHUNK;
  const unsigned short* Ab_l = Bt_l + ((size_t)cb * DV + dt * 128) * CHUNK;

  float4_t acc[4][2];
#pragma unroll
  for (int i = 0; i < 4; ++i)
#pragma unroll
    for (int j = 0; j < 2; ++j) acc[i][j] = (float4_t)0.0f;

  for (int ks = 0; ks < 4; ++ks) {
    const int k0 = ks * 32;
#pragma unroll
    for (int q = 0; q < 2; ++q) {
      const int flat = (q * 256 + tid) * 8;
      const int row = flat >> 5, col = flat & 31;
      gload16(&Ab_h[(size_t)row * CHUNK + k0 + col], &Ah[flat]);
      gload16(&Ab_l[(size_t)row * CHUNK + k0 + col], &Al[flat]);
    }

    short8_t b_hi[2], b_lo[2];
#pragma unroll
    for (int j = 0; j < 2; ++j) {
      const int n = wn + j * 16 + fm;
#pragma unroll
      for (int e = 0; e < 8; ++e) {
        const float kv = k_ws[(size_t)(c * CHUNK + k0 + fk + e) * 256 + b * 64 + n];
        const unsigned short h = f2bf(kv);
        b_hi[j][e] = (short)h;
        b_lo[j][e] = (short)f2bf(kv - bf2f(h));
      }
    }
    __syncthreads();

    short8_t a_hi[4], a_lo[4];
#pragma unroll
    for (int i = 0; i < 4; ++i) {
      const int ar = (wm + i * 16 + fm) * 32 + fk;
      a_hi[i] = *(const short8_t*)&Ah[ar];
      a_lo[i] = *(const short8_t*)&Al[ar];
    }
#pragma unroll
    for (int i = 0; i < 4; ++i)
#pragma unroll
      for (int j = 0; j < 2; ++j) {
        acc[i][j] = __builtin_amdgcn_mfma_f32_16x16x32_bf16(a_hi[i], b_hi[j], acc[i][j], 0, 0, 0);
        acc[i][j] = __builtin_amdgcn_mfma_f32_16x16x32_bf16(a_lo[i], b_hi[j], acc[i][j], 0, 0, 0);
        acc[i][j] = __builtin_amdgcn_mfma_f32_16x16x32_bf16(a_hi[i], b_lo[j], acc[i][j], 0, 0, 0);
      }
    __syncthreads();
  }

#pragma unroll
  for (int j = 0; j < 2; ++j) {
    const int n = wn + j * 16 + fm;
    const float pj = pend[c * 256 + b * 64 + n];
#pragma unroll
    for (int i = 0; i < 4; ++i) {
#pragma unroll
      for (int r = 0; r < 4; ++r) {
        const int dd = dt * 128 + wm + i * 16 + (lane >> 4) * 4 + r;
        W_ws[((size_t)cb * DV + dd) * DK + n] = acc[i][j][r] * pj;
      }
    }
  }
}

// ---------------------------------------------------------------------------
// K4: sequential state scan over chunks.  Emits pre-update state S_c as
// split-bf16 (Sh/Sl) for out_mfma's uniform global_load_lds staging.
// ---------------------------------------------------------------------------
__global__ __launch_bounds__(256) void scan_kernel(
    const float* __restrict__ W_ws, const float* __restrict__ pend,
    unsigned short* __restrict__ Sh, unsigned short* __restrict__ Sl)
{
  const int flat = blockIdx.x * 256 + threadIdx.x;
  const int n = flat & 63;
  const int bd = flat >> 6;
  const int b = bd >> 9;
  float s = 0.0f;
  for (int c = 0; c < NCH; ++c) {
    const int off = c * 131072 + flat;
    const float w = W_ws[off];
    const unsigned short h = f2bf(s);
    Sh[off] = h;
    Sl[off] = f2bf(s - bf2f(h));
    s = s * pend[c * 256 + b * 64 + n] + w;
  }
}

// ---------------------------------------------------------------------------
// K5: A = tril(q_t @ k_t^T) via MFMA.  Single K=64 step, [128][64]
// XOR-swizzled tiles.
// ---------------------------------------------------------------------------
__global__ __launch_bounds__(256) void score_mfma_kernel(
    const float* __restrict__ k_ws,
    unsigned short* __restrict__ Acat_h, unsigned short* __restrict__ Acat_l)
{
  __shared__ __align__(16) unsigned short Ah[128 * 64];
  __shared__ __align__(16) unsigned short Al[128 * 64];
  __shared__ __align__(16) unsigned short Bh[128 * 64];
  __shared__ __align__(16) unsigned short Bl[128 * 64];

  const int c = blockIdx.x, b = blockIdx.y;
  const int cb = c * B_DIM + b;
  const int tid  = threadIdx.x;
  const int wave = tid >> 6, lane = tid & 63;
  const int wm   = (wave & 1) * 64, wn = (wave >> 1) * 64;
  const int fm   = lane & 15;
  const int fk   = (lane >> 4) * 8;

  const unsigned short* Aq_h = Acat_h + (size_t)cb * CHUNK * KCAT + 128;
  const unsigned short* Aq_l = Acat_l + (size_t)cb * CHUNK * KCAT + 128;

  const int srow = tid >> 3;          // 0..31
  const int scolB = (tid & 7) * 16;   // byte col
  const int sc = (scolB ^ ((srow & 7) << 4)) >> 1;   // halfs
  const int sdst = srow * 64 + (scolB >> 1);
#pragma unroll
  for (int q = 0; q < 4; ++q) {
    const int row = q * 32 + srow;
    const int dst = q * 2048 + sdst;
    gload16(&Aq_h[(size_t)row * KCAT + sc], &Ah[dst]);
    gload16(&Aq_l[(size_t)row * KCAT + sc], &Al[dst]);
  }
#pragma unroll
  for (int q = 0; q < 8; ++q) {
    const int f = (q * 256 + tid) * 4;
    const int s = f >> 6, n0 = f & 63;
    const float4 kv = *(const float4*)&k_ws[(size_t)(c * CHUNK + s) * 256 + b * 64 + n0];
    ushort4 h, l;
    h.x = f2bf(kv.x); l.x = f2bf(kv.x - bf2f(h.x));
    h.y = f2bf(kv.y); l.y = f2bf(kv.y - bf2f(h.y));
    h.z = f2bf(kv.z); l.z = f2bf(kv.z - bf2f(h.z));
    h.w = f2bf(kv.w); l.w = f2bf(kv.w - bf2f(h.w));
    const int wi = s * 64 + (n0 ^ ((s & 7) << 3));
    *(ushort4*)&Bh[wi] = h;
    *(ushort4*)&Bl[wi] = l;
  }
  __syncthreads();

  float4_t acc[4][4];
#pragma unroll
  for (int i = 0; i < 4; ++i)
#pragma unroll
    for (int j = 0; j < 4; ++j) acc[i][j] = (float4_t)0.0f;

#pragma unroll
  for (int ksub = 0; ksub < 2; ++ksub) {
    short8_t a_hi[4], a_lo[4], b_hi[4], b_lo[4];
#pragma unroll
    for (int i = 0; i < 4; ++i) {
      const int r = wm + i * 16 + fm;
      const int ar = r * 64 + ((ksub * 32 + fk) ^ ((r & 7) << 3));
      a_hi[i] = *(const short8_t*)&Ah[ar];
      a_lo[i] = *(const short8_t*)&Al[ar];
    }
#pragma unroll
    for (int j = 0; j < 4; ++j) {
      const int r = wn + j * 16 + fm;
      const int br = r * 64 + ((ksub * 32 + fk) ^ ((r & 7) << 3));
      b_hi[j] = *(const short8_t*)&Bh[br];
      b_lo[j] = *(const short8_t*)&Bl[br];
    }
    __builtin_amdgcn_s_setprio(1);
#pragma unroll
    for (int i = 0; i < 4; ++i)
#pragma unroll
      for (int j = 0; j < 4; ++j) {
        acc[i][j] = __builtin_amdgcn_mfma_f32_16x16x32_bf16(a_hi[i], b_hi[j], acc[i][j], 0, 0, 0);
        acc[i][j] = __builtin_amdgcn_mfma_f32_16x16x32_bf16(a_lo[i], b_hi[j], acc[i][j], 0, 0, 0);
        acc[i][j] = __builtin_amdgcn_mfma_f32_16x16x32_bf16(a_hi[i], b_lo[j], acc[i][j], 0, 0, 0);
      }
    __builtin_amdgcn_s_setprio(0);
  }

#pragma unroll
  for (int j = 0; j < 4; ++j) {
    const int s = wn + j * 16 + fm;
#pragma unroll
    for (int i = 0; i < 4; ++i) {
#pragma unroll
      for (int r = 0; r < 4; ++r) {
        const int t = wm + i * 16 + (lane >> 4) * 4 + r;
        const float vv = (s <= t) ? acc[i][j][r] : 0.0f;
        const unsigned short h = f2bf(vv);
        const size_t oa = ((size_t)cb * CHUNK + t) * KCAT + s;
        Acat_h[oa] = h;
        Acat_l[oa] = f2bf(vv - bf2f(h));
      }
    }
  }
}

// ---------------------------------------------------------------------------
// K6: y = [A|q_t] @ [v ; S^T].  3 uniform K=64 XOR-swizzled steps.
// 1D grid, XCD-grouped so the 4 nt-blocks of one (c,b) share an XCD's L2
// (Acat tile re-read x4 becomes L2-resident).
// ---------------------------------------------------------------------------
__global__ __launch_bounds__(256) void out_mfma_kernel(
    const unsigned short* __restrict__ Acat_h, const unsigned short* __restrict__ Acat_l,
    const unsigned short* __restrict__ Bt_h, const unsigned short* __restrict__ Bt_l,
    const unsigned short* __restrict__ Sh, const unsigned short* __restrict__ Sl,
    float* __restrict__ out)
{
  __shared__ __align__(16) unsigned short Ah[128 * 64];
  __shared__ __align__(16) unsigned short Al[128 * 64];
  __shared__ __align__(16) unsigned short Bh[128 * 64];
  __shared__ __align__(16) unsigned short Bl[128 * 64];

  const int bd = blockIdx.x;
  const int cb = (bd >> 5) * 8 + (bd & 7);
  const int nt = (bd >> 3) & 3;
  const int c = cb >> 2, b = cb & 3;
  const int tid  = threadIdx.x;
  const int wave = tid >> 6, lane = tid & 63;
  const int wm   = (wave & 1) * 64, wn = (wave >> 1) * 64;
  const int fm   = lane & 15;
  const int fk   = (lane >> 4) * 8;

  const unsigned short* Ab_h = Acat_h + (size_t)cb * CHUNK * KCAT;
  const unsigned short* Ab_l = Acat_l + (size_t)cb * CHUNK * KCAT;
  const unsigned short* Bb_h = Bt_h + ((size_t)cb * DV + nt * 128) * CHUNK;
  const unsigned short* Bb_l = Bt_l + ((size_t)cb * DV + nt * 128) * CHUNK;
  const unsigned short* Sb_h = Sh + ((size_t)cb * DV + nt * 128) * DK;
  const unsigned short* Sb_l = Sl + ((size_t)cb * DV + nt * 128) * DK;

  const int srow = tid >> 3;          // 0..31
  const int scolB = (tid & 7) * 16;
  const int sc = (scolB ^ ((srow & 7) << 4)) >> 1;   // halfs
  const int sdst = srow * 64 + (scolB >> 1);

  float4_t acc[4][4];
#pragma unroll
  for (int i = 0; i < 4; ++i)
#pragma unroll
    for (int j = 0; j < 4; ++j) acc[i][j] = (float4_t)0.0f;

  for (int ks = 0; ks < 3; ++ks) {
    const int k0 = ks * 64;
#pragma unroll
    for (int q = 0; q < 4; ++q) {
      const int row = q * 32 + srow;
      const int dst = q * 2048 + sdst;
      gload16(&Ab_h[(size_t)row * KCAT + k0 + sc], &Ah[dst]);
      gload16(&Ab_l[(size_t)row * KCAT + k0 + sc], &Al[dst]);
      if (ks < 2) {
        gload16(&Bb_h[(size_t)row * CHUNK + k0 + sc], &Bh[dst]);
        gload16(&Bb_l[(size_t)row * CHUNK + k0 + sc], &Bl[dst]);
      } else {
        gload16(&Sb_h[(size_t)row * DK + sc], &Bh[dst]);
        gload16(&Sb_l[(size_t)row * DK + sc], &Bl[dst]);
      }
    }
    __syncthreads();

#pragma unroll
    for (int ksub = 0; ksub < 2; ++ksub) {
      short8_t a_hi[4], a_lo[4], b_hi[4], b_lo[4];
#pragma unroll
      for (int i = 0; i < 4; ++i) {
        const int r = wm + i * 16 + fm;
        const int ar = r * 64 + ((ksub * 32 + fk) ^ ((r & 7) << 3));
        a_hi[i] = *(const short8_t*)&Ah[ar];
        a_lo[i] = *(const short8_t*)&Al[ar];
      }
#pragma unroll
      for (int j = 0; j < 4; ++j) {
        const int r = wn + j * 16 + fm;
        const int br = r * 64 + ((ksub * 32 + fk) ^ ((r & 7) << 3));
        b_hi[j] = *(const short8_t*)&Bh[br];
        b_lo[j] = *(const short8_t*)&Bl[br];
      }
      __builtin_amdgcn_s_setprio(1);
#pragma unroll
      for (int i = 0; i < 4; ++i)
#pragma unroll
        for (int j = 0; j < 4; ++j) {
          acc[i][j] = __builtin_amdgcn_mfma_f32_16x16x32_bf16(a_hi[i], b_hi[j], acc[i][j], 0, 0, 0);
          acc[i][j] = __builtin_amdgcn_mfma_f32_16x16x32_bf16(a_lo[i], b_hi[j], acc[i][j], 0, 0, 0);
          acc[i][j] = __builtin_amdgcn_mfma_f32_16x16x32_bf16(a_hi[i], b_lo[j], acc[i][j], 0, 0, 0);
        }
      __builtin_amdgcn_s_setprio(0);
    }
    __syncthreads();
  }

#pragma unroll
  for (int j = 0; j < 4; ++j) {
    const int d = nt * 128 + wn + j * 16 + fm;
#pragma unroll
    for (int i = 0; i < 4; ++i) {
#pragma unroll
      for (int r = 0; r < 4; ++r) {
        const int t = c * CHUNK + wm + i * 16 + (lane >> 4) * 4 + r;
        out[((size_t)t * B_DIM + b) * DV + d] = acc[i][j][r];
      }
    }
  }
}

// ---------------------------------------------------------------------------
extern "C" void kernel_launch(void* const* d_in, const int* in_sizes, int n_in,
                              void* d_out, int out_size, void* d_ws, size_t ws_size,
                              hipStream_t stream)
{
  const float* x  = (const float*)d_in[0];
  const float* Wv = (const float*)d_in[1];
  const float* bv = (const float*)d_in[2];
  const float* Wk = (const float*)d_in[3];
  const float* bk = (const float*)d_in[4];
  const float* Wq = (const float*)d_in[5];
  const float* bq = (const float*)d_in[6];
  const float* Wa = (const float*)d_in[7];
  const float* ba = (const float*)d_in[8];
  float* out = (float*)d_out;

  // ---- workspace layout ----
  float* ws   = (float*)d_ws;
  // Bt occupies the old v_ws span (64 MB), written directly by proj.
  unsigned short* Bt_h = (unsigned short*)ws;               // 16,777,216 us
  unsigned short* Bt_l = Bt_h + (size_t)NCH * B_DIM * DV * CHUNK;
  float* k_ws = ws + (size_t)ROWS * DV;                     //  2,097,152 f
  float* a_ws = k_ws + (size_t)ROWS * DK;                   //  2,097,152 f
  float* pend = a_ws + (size_t)ROWS * DK;                   //     16,384 f
  float* W_ws = pend + NCH * B_DIM * DK;                    //  8,388,608 f
  float* bcat = W_ws + (size_t)NCH * B_DIM * DV * DK;       //        768 f
  unsigned short* Acat_h = (unsigned short*)(bcat + NPAD);  //  6,291,456 us
  unsigned short* Acat_l = Acat_h + (size_t)NCH * B_DIM * CHUNK * KCAT;
  unsigned short* uni = Acat_l + (size_t)NCH * B_DIM * CHUNK * KCAT;
  // union: fp16 proj staging (dead after proj_mfma)
  unsigned short* xh = uni;                                 // 16,777,216 us
  unsigned short* wh = xh + (size_t)ROWS * INDIM;           //    393,216 us
  // q_ws: fp32 q staging at uni+36MB (consumed by prep; no overlap w/ Sh/Sl)
  float* q_ws = (float*)(uni + (size_t)18 * 1024 * 1024);   //  2,097,152 f
  // Sh/Sl: split-bf16 state over dead xh (written by scan, read by out)
  unsigned short* S_h = uni;                                //  8,388,608 us
  unsigned short* S_l = S_h + (size_t)NCH * B_DIM * DV * DK;

  cast_kernel<<<16384 + 384, 256, 0, stream>>>(
      x, Wv, Wk, Wq, Wa, bv, bk, bq, ba, xh, wh, bcat);
  proj_mfma_kernel<<<(ROWS / 128) * (NPAD / 128), 256, 0, stream>>>(
      xh, wh, bcat, Bt_h, Bt_l, k_ws, q_ws, a_ws);
  prep_kernel<<<dim3(NCH, B_DIM), 512, 0, stream>>>(
      a_ws, k_ws, q_ws, Acat_h, Acat_l, pend);
  wchunk_mfma_kernel<<<NCH * B_DIM * 4, 256, 0, stream>>>(
      Bt_h, Bt_l, k_ws, pend, W_ws);
  scan_kernel<<<(B_DIM * DV * DK) / 256, 256, 0, stream>>>(
      W_ws, pend, S_h, S_l);
  score_mfma_kernel<<<dim3(NCH, B_DIM), 256, 0, stream>>>(
      k_ws, Acat_h, Acat_l);
  out_mfma_kernel<<<NCH * B_DIM * 4, 256, 0, stream>>>(
      Acat_h, Acat_l, Bt_h, Bt_l, S_h, S_l, out);
}

// Round 5
// 260.131 us; speedup vs baseline: 1.2707x; 1.0374x over previous
//
#include <hip/hip_runtime.h>
#include <math.h>

#define T_DIM 8192
#define B_DIM 4
#define INDIM 512
#define DV 512
#define DK 64
#define CHUNK 128
#define NCH (T_DIM / CHUNK)     // 64
#define ROWS (T_DIM * B_DIM)    // 32768
#define NPAD 768                // 704 proj cols padded to 6x128
#define KCAT 192                // 128 intra + 64 state
#define EPSF 1e-8f

typedef float float4_t __attribute__((ext_vector_type(4)));
typedef short short8_t __attribute__((ext_vector_type(8)));
typedef _Float16 half8_t __attribute__((ext_vector_type(8)));

__device__ inline unsigned short f2bf(float f) {
  unsigned int u = __float_as_uint(f);
  unsigned int r = (u + 0x7fffu + ((u >> 16) & 1u)) >> 16;
  return (unsigned short)r;
}
__device__ inline float bf2f(unsigned short h) {
  return __uint_as_float(((unsigned int)h) << 16);
}
__device__ inline unsigned short f2h(float f) {
  _Float16 h = (_Float16)f;
  unsigned short u;
  __builtin_memcpy(&u, &h, 2);
  return u;
}

__device__ inline void gload16(const void* g, void* l) {
  __builtin_amdgcn_global_load_lds(
      (const __attribute__((address_space(1))) void*)g,
      (__attribute__((address_space(3))) void*)l, 16, 0, 0);
}

// ---------------------------------------------------------------------------
// C0: merged fp16 cast.  blocks [0,16384): x -> xh (fp16).
// blocks [16384,16768): padded concat weights -> wh (fp16) + bcat.
// ---------------------------------------------------------------------------
__global__ __launch_bounds__(256) void cast_kernel(
    const float* __restrict__ x,
    const float* __restrict__ Wv, const float* __restrict__ Wk,
    const float* __restrict__ Wq, const float* __restrict__ Wa,
    const float* __restrict__ bv, const float* __restrict__ bk,
    const float* __restrict__ bq, const float* __restrict__ ba,
    unsigned short* __restrict__ xh, unsigned short* __restrict__ wh,
    float* __restrict__ bcat)
{
  if (blockIdx.x < 16384) {
    const size_t i4 = ((size_t)blockIdx.x * 256 + threadIdx.x) * 4;
    const float4 v = *(const float4*)&x[i4];
    ushort4 h;
    h.x = f2h(v.x); h.y = f2h(v.y); h.z = f2h(v.z); h.w = f2h(v.w);
    *(ushort4*)&xh[i4] = h;
  } else {
    const int t = (blockIdx.x - 16384) * 256 + threadIdx.x;
    const size_t i4 = (size_t)t * 4;
    const int row = (int)(i4 >> 9);
    const int col = (int)(i4 & 511);
    float4 v = {0.f, 0.f, 0.f, 0.f};
    if (row < 512)      v = *(const float4*)&Wv[(size_t)row * INDIM + col];
    else if (row < 576) v = *(const float4*)&Wk[(size_t)(row - 512) * INDIM + col];
    else if (row < 640) v = *(const float4*)&Wq[(size_t)(row - 576) * INDIM + col];
    else if (row < 704) v = *(const float4*)&Wa[(size_t)(row - 640) * INDIM + col];
    ushort4 h;
    h.x = f2h(v.x); h.y = f2h(v.y); h.z = f2h(v.z); h.w = f2h(v.w);
    *(ushort4*)&wh[i4] = h;
    if (t < NPAD) {
      float b = 0.f;
      if (t < 512)      b = bv[t];
      else if (t < 576) b = bk[t - 512];
      else if (t < 640) b = bq[t - 576];
      else if (t < 704) b = ba[t - 640];
      bcat[t] = b;
    }
  }
}

// ---------------------------------------------------------------------------
// K1: fp16 MFMA projection GEMM (M=32768,K=512,N=768), fp32 accumulate.
// v-columns (xtile<4) transposed in-LDS, written directly as split-bf16
// Bt[(cb)][d][s].  3-buffer ring, depth-2 prefetch, XCD-grouped mapping.
// ---------------------------------------------------------------------------
__global__ __launch_bounds__(256) void proj_mfma_kernel(
    const unsigned short* __restrict__ xh, const unsigned short* __restrict__ wh,
    const float* __restrict__ bcat,
    unsigned short* __restrict__ Bt_h, unsigned short* __restrict__ Bt_l,
    float* __restrict__ k_ws, float* __restrict__ q_ws,
    float* __restrict__ a_ws)
{
  __shared__ __align__(16) _Float16 Ah[3][128 * 32];   // 24 KB
  __shared__ __align__(16) _Float16 Bh[3][128 * 32];   // 24 KB

  const int d     = blockIdx.x;
  const int grp   = d >> 3;                 // 0..191
  const int ytile = (d & 7) * 32 + grp / 6; // 0..255
  const int xtile = grp % 6;                // 0..5
  const int r0 = ytile * 128;
  const int c0 = xtile * 128;

  const int tid  = threadIdx.x;
  const int wave = tid >> 6, lane = tid & 63;
  const int wm   = (wave & 1) * 64, wn = (wave >> 1) * 64;
  const int fm   = lane & 15;
  const int fk   = (lane >> 4) * 8;
  const int g    = lane >> 4;

  float4_t acc[4][4];
#pragma unroll
  for (int i = 0; i < 4; ++i)
#pragma unroll
    for (int j = 0; j < 4; ++j) acc[i][j] = (float4_t)0.0f;

  const int srow = tid >> 2;           // 0..63
  const int scol = (tid & 3) * 8;      // 0,8,16,24

  const unsigned short* pA0 = xh + (size_t)(r0 + srow) * INDIM + scol;
  const unsigned short* pA1 = xh + (size_t)(r0 + 64 + srow) * INDIM + scol;
  const unsigned short* pB0 = wh + (size_t)(c0 + srow) * INDIM + scol;
  const unsigned short* pB1 = wh + (size_t)(c0 + 64 + srow) * INDIM + scol;

  auto stage = [&](int buf, int k0) {
    gload16(pA0 + k0, &Ah[buf][tid * 8]);
    gload16(pA1 + k0, &Ah[buf][(256 + tid) * 8]);
    gload16(pB0 + k0, &Bh[buf][tid * 8]);
    gload16(pB1 + k0, &Bh[buf][(256 + tid) * 8]);
  };

  auto compute = [&](int buf) {
    half8_t a[4], b[4];
#pragma unroll
    for (int i = 0; i < 4; ++i)
      a[i] = *(const half8_t*)&Ah[buf][(wm + i * 16 + fm) * 32 + fk];
#pragma unroll
    for (int j = 0; j < 4; ++j)
      b[j] = *(const half8_t*)&Bh[buf][(wn + j * 16 + fm) * 32 + fk];
    __builtin_amdgcn_s_setprio(1);
#pragma unroll
    for (int i = 0; i < 4; ++i)
#pragma unroll
      for (int j = 0; j < 4; ++j)
        acc[i][j] = __builtin_amdgcn_mfma_f32_16x16x32_f16(a[i], b[j], acc[i][j], 0, 0, 0);
    __builtin_amdgcn_s_setprio(0);
  };

  stage(0, 0);
  stage(1, 32);
  int cur = 0;
  for (int t = 0; t < 14; ++t) {
    stage((cur + 2) % 3, (t + 2) * 32);
    asm volatile("s_waitcnt vmcnt(8)" ::: "memory");
    __builtin_amdgcn_s_barrier();
    compute(cur);
    __builtin_amdgcn_s_barrier();
    cur = (cur + 1) % 3;
  }
  asm volatile("s_waitcnt vmcnt(4)" ::: "memory");
  __builtin_amdgcn_s_barrier();
  compute(cur);
  cur = (cur + 1) % 3;
  asm volatile("s_waitcnt vmcnt(0)" ::: "memory");
  __builtin_amdgcn_s_barrier();
  compute(cur);

  if (xtile < 4) {
    // ---- v path: LDS transpose -> Bt split-bf16 ----
    unsigned int* Thl = (unsigned int*)&Ah[0][0];
    const int t0 = r0 >> 2;            // multiple of 32
    const int cb0 = (t0 >> 7) * 4;     // chunk*4
    const int s0 = t0 & 127;           // 0/32/64/96
    __syncthreads();
    for (int bb = 0; bb < 4; ++bb) {
#pragma unroll
      for (int j = 0; j < 4; ++j) {
        const int d_loc = wn + j * 16 + fm;
        const float bias = bcat[c0 + d_loc];
#pragma unroll
        for (int i = 0; i < 4; ++i) {
          const int trow = (wm >> 2) + i * 4 + g;       // 0..31
          const float val = acc[i][j][bb] + bias;
          const unsigned short h = f2bf(val);
          const unsigned short l = f2bf(val - bf2f(h));
          Thl[d_loc * 34 + trow] = (unsigned int)h | ((unsigned int)l << 16);
        }
      }
      __syncthreads();
#pragma unroll
      for (int q2 = 0; q2 < 4; ++q2) {
        const int task = q2 * 256 + tid;   // 0..1023
        const int dd = task >> 3;          // 0..127
        const int tq = task & 7;           // 0..7
        const unsigned int* p = &Thl[dd * 34 + tq * 4];
        const unsigned int w0 = p[0], w1 = p[1], w2 = p[2], w3 = p[3];
        ushort4 hh, ll;
        hh.x = (unsigned short)w0; ll.x = (unsigned short)(w0 >> 16);
        hh.y = (unsigned short)w1; ll.y = (unsigned short)(w1 >> 16);
        hh.z = (unsigned short)w2; ll.z = (unsigned short)(w2 >> 16);
        hh.w = (unsigned short)w3; ll.w = (unsigned short)(w3 >> 16);
        const size_t oa = ((size_t)(cb0 + bb) * DV + c0 + dd) * CHUNK + s0 + tq * 4;
        *(ushort4*)&Bt_h[oa] = hh;
        *(ushort4*)&Bt_l[oa] = ll;
      }
      __syncthreads();
    }
  } else {
    // ---- k/q/a path: coalesced fp32 stores ----
#pragma unroll
    for (int j = 0; j < 4; ++j) {
      const int col = c0 + wn + j * 16 + fm;
      if (col >= 704) continue;
      const float bias = bcat[col];
#pragma unroll
      for (int i = 0; i < 4; ++i) {
#pragma unroll
        for (int r = 0; r < 4; ++r) {
          const int row = r0 + wm + i * 16 + g * 4 + r;  // row = t*4+b
          const float val = acc[i][j][r] + bias;
          if (col < 576) {
            k_ws[(size_t)row * DK + col - 512] = val;
          } else if (col < 640) {
            q_ws[(size_t)row * DK + col - 576] = val;
          } else {
            a_ws[(size_t)row * DK + col - 640] = 1.0f / (1.0f + expf(-val));
          }
        }
      }
    }
  }
}

// ---------------------------------------------------------------------------
// K2: fused prep+score per (c,b).  512 threads, 96 KB LDS, 1 block/CU.
// cumprod -> q pass (Acat q-cols + LDS tile) -> k pass (LDS tile only,
// no k_ws RMW) -> kT transpose (split-bf16 [cb][n][t] for wchunk) ->
// 8-wave score MFMA from LDS -> tril s-col write.  Numerics identical to
// the previous prep+score pair (same f2bf of same floats, same order).
// ---------------------------------------------------------------------------
__global__ __launch_bounds__(512) void prep_kernel(
    const float* __restrict__ a_ws, const float* __restrict__ k_ws,
    const float* __restrict__ q_ws,
    unsigned short* __restrict__ Acat_h, unsigned short* __restrict__ Acat_l,
    unsigned short* __restrict__ kT_h, unsigned short* __restrict__ kT_l,
    float* __restrict__ pend)
{
  __shared__ float pal[CHUNK][DK];                        // 32 KB
  __shared__ __align__(16) unsigned short Aq_h[128 * 64]; // 16 KB
  __shared__ __align__(16) unsigned short Aq_l[128 * 64]; // 16 KB
  __shared__ __align__(16) unsigned short Bk_h[128 * 64]; // 16 KB
  __shared__ __align__(16) unsigned short Bk_l[128 * 64]; // 16 KB

  const int c = blockIdx.x, b = blockIdx.y;
  const int cb = c * B_DIM + b;
  const int tid = threadIdx.x;
  const int wave = tid >> 6, lane = tid & 63;
  const int wm = (wave & 1) * 64, wn = (wave >> 1) * 32;
  const int fm = lane & 15;
  const int fk = (lane >> 4) * 8;
  const int g  = lane >> 4;

  // alpha -> pal
#pragma unroll
  for (int i = 0; i < 4; ++i) {
    const int f = (i * 512 + tid) * 4;       // 0..8191
    const int t = f >> 6, n0 = f & 63;
    const float4 av = *(const float4*)&a_ws[(size_t)(c * CHUNK + t) * 256 + b * 64 + n0];
    *(float4*)&pal[t][n0] = av;
  }
  __syncthreads();

  if (tid < 64) {
    float p = 1.0f;
#pragma unroll 4
    for (int t = 0; t < CHUNK; ++t) {
      p *= fmaxf(pal[t][tid], EPSF);
      pal[t][tid] = p;
    }
    pend[c * 256 + b * 64 + tid] = p;
  }
  __syncthreads();

  // q pass: Acat q-cols (global) + swizzled LDS tile
#pragma unroll
  for (int i = 0; i < 4; ++i) {
    const int f = (i * 512 + tid) * 4;
    const int t = f >> 6, n0 = f & 63;
    const float4 qv = *(const float4*)&q_ws[(size_t)(c * CHUNK + t) * 256 + b * 64 + n0];
    const size_t qa = ((size_t)cb * CHUNK + t) * KCAT + 128 + n0;
    float q0 = qv.x * pal[t][n0 + 0];
    float q1 = qv.y * pal[t][n0 + 1];
    float q2 = qv.z * pal[t][n0 + 2];
    float q3 = qv.w * pal[t][n0 + 3];
    ushort4 h, l;
    h.x = f2bf(q0); l.x = f2bf(q0 - bf2f(h.x));
    h.y = f2bf(q1); l.y = f2bf(q1 - bf2f(h.y));
    h.z = f2bf(q2); l.z = f2bf(q2 - bf2f(h.z));
    h.w = f2bf(q3); l.w = f2bf(q3 - bf2f(h.w));
    *(ushort4*)&Acat_h[qa] = h;
    *(ushort4*)&Acat_l[qa] = l;
    const int wi = t * 64 + (n0 ^ ((t & 7) << 3));
    *(ushort4*)&Aq_h[wi] = h;
    *(ushort4*)&Aq_l[wi] = l;
  }

  // k pass: swizzled LDS tile only (k_ws stays raw; no RMW)
#pragma unroll
  for (int i = 0; i < 4; ++i) {
    const int f = (i * 512 + tid) * 4;
    const int t = f >> 6, n0 = f & 63;
    const float4 kv = *(const float4*)&k_ws[(size_t)(c * CHUNK + t) * 256 + b * 64 + n0];
    float k0 = kv.x / (pal[t][n0 + 0] + EPSF);
    float k1 = kv.y / (pal[t][n0 + 1] + EPSF);
    float k2 = kv.z / (pal[t][n0 + 2] + EPSF);
    float k3 = kv.w / (pal[t][n0 + 3] + EPSF);
    ushort4 h, l;
    h.x = f2bf(k0); l.x = f2bf(k0 - bf2f(h.x));
    h.y = f2bf(k1); l.y = f2bf(k1 - bf2f(h.y));
    h.z = f2bf(k2); l.z = f2bf(k2 - bf2f(h.z));
    h.w = f2bf(k3); l.w = f2bf(k3 - bf2f(h.w));
    const int wi = t * 64 + (n0 ^ ((t & 7) << 3));
    *(ushort4*)&Bk_h[wi] = h;
    *(ushort4*)&Bk_l[wi] = l;
  }
  __syncthreads();

  // kT transpose: Bk -> kT[cb][n][t] split-bf16, coalesced 16B rows.
#pragma unroll
  for (int it = 0; it < 2; ++it) {
    const int task = it * 512 + tid;    // 0..1023
    const int n  = task >> 4;           // 0..63
    const int tg = task & 15;           // 0..15
    ushort4 h0, h1, l0, l1;
    unsigned short hh[8], ll[8];
#pragma unroll
    for (int e = 0; e < 8; ++e) {
      const int wi = (tg * 8 + e) * 64 + (n ^ (e << 3));
      hh[e] = Bk_h[wi];
      ll[e] = Bk_l[wi];
    }
    h0.x = hh[0]; h0.y = hh[1]; h0.z = hh[2]; h0.w = hh[3];
    h1.x = hh[4]; h1.y = hh[5]; h1.z = hh[6]; h1.w = hh[7];
    l0.x = ll[0]; l0.y = ll[1]; l0.z = ll[2]; l0.w = ll[3];
    l1.x = ll[4]; l1.y = ll[5]; l1.z = ll[6]; l1.w = ll[7];
    const size_t oa = ((size_t)cb * DK + n) * CHUNK + tg * 8;
    *(ushort4*)&kT_h[oa]     = h0;
    *(ushort4*)&kT_h[oa + 4] = h1;
    *(ushort4*)&kT_l[oa]     = l0;
    *(ushort4*)&kT_l[oa + 4] = l1;
  }

  // score: A = tril(q_t @ k_t^T), 8 waves x (64x32 quadrant)
  float4_t acc[4][2];
#pragma unroll
  for (int i = 0; i < 4; ++i)
#pragma unroll
    for (int j = 0; j < 2; ++j) acc[i][j] = (float4_t)0.0f;

#pragma unroll
  for (int ksub = 0; ksub < 2; ++ksub) {
    short8_t a_hi[4], a_lo[4], b_hi[2], b_lo[2];
#pragma unroll
    for (int i = 0; i < 4; ++i) {
      const int r = wm + i * 16 + fm;
      const int ar = r * 64 + ((ksub * 32 + fk) ^ ((r & 7) << 3));
      a_hi[i] = *(const short8_t*)&Aq_h[ar];
      a_lo[i] = *(const short8_t*)&Aq_l[ar];
    }
#pragma unroll
    for (int j = 0; j < 2; ++j) {
      const int r = wn + j * 16 + fm;
      const int br = r * 64 + ((ksub * 32 + fk) ^ ((r & 7) << 3));
      b_hi[j] = *(const short8_t*)&Bk_h[br];
      b_lo[j] = *(const short8_t*)&Bk_l[br];
    }
    __builtin_amdgcn_s_setprio(1);
#pragma unroll
    for (int i = 0; i < 4; ++i)
#pragma unroll
      for (int j = 0; j < 2; ++j) {
        acc[i][j] = __builtin_amdgcn_mfma_f32_16x16x32_bf16(a_hi[i], b_hi[j], acc[i][j], 0, 0, 0);
        acc[i][j] = __builtin_amdgcn_mfma_f32_16x16x32_bf16(a_lo[i], b_hi[j], acc[i][j], 0, 0, 0);
        acc[i][j] = __builtin_amdgcn_mfma_f32_16x16x32_bf16(a_hi[i], b_lo[j], acc[i][j], 0, 0, 0);
      }
    __builtin_amdgcn_s_setprio(0);
  }

#pragma unroll
  for (int j = 0; j < 2; ++j) {
    const int s = wn + j * 16 + fm;
#pragma unroll
    for (int i = 0; i < 4; ++i) {
#pragma unroll
      for (int r = 0; r < 4; ++r) {
        const int t = wm + i * 16 + g * 4 + r;
        const float vv = (s <= t) ? acc[i][j][r] : 0.0f;
        const unsigned short h = f2bf(vv);
        const size_t oa = ((size_t)cb * CHUNK + t) * KCAT + s;
        Acat_h[oa] = h;
        Acat_l[oa] = f2bf(vv - bf2f(h));
      }
    }
  }
}

// ---------------------------------------------------------------------------
// K3: wchunk via MFMA.  W[d][n] = (sum_t v^T[d][t]*k_t[t][n]) * pend[n].
// B-operand from kT (split-bf16, staged once via slot-swizzled gload16);
// no scalar k loads, no in-kernel conversion.  XCD-grouped 1D grid.
// ---------------------------------------------------------------------------
__global__ __launch_bounds__(256) void wchunk_mfma_kernel(
    const unsigned short* __restrict__ Bt_h, const unsigned short* __restrict__ Bt_l,
    const unsigned short* __restrict__ kT_h, const unsigned short* __restrict__ kT_l,
    const float* __restrict__ pend, float* __restrict__ W_ws)
{
  __shared__ __align__(16) unsigned short Ah[128 * 32];  //  8 KB
  __shared__ __align__(16) unsigned short Al[128 * 32];  //  8 KB
  __shared__ __align__(16) unsigned short Kh[64 * 128];  // 16 KB
  __shared__ __align__(16) unsigned short Kl[64 * 128];  // 16 KB

  const int bd = blockIdx.x;
  const int cb = (bd >> 5) * 8 + (bd & 7);
  const int dt = (bd >> 3) & 3;
  const int c = cb >> 2, b = cb & 3;
  (void)c; (void)b;
  const int tid  = threadIdx.x;
  const int wave = tid >> 6, lane = tid & 63;
  const int wm   = (wave & 1) * 64;
  const int wn   = (wave >> 1) * 32;
  const int fm   = lane & 15;
  const int fk   = (lane >> 4) * 8;

  const unsigned short* Ab_h = Bt_h + ((size_t)cb * DV + dt * 128) * CHUNK;
  const unsigned short* Ab_l = Bt_l + ((size_t)cb * DV + dt * 128) * CHUNK;
  const unsigned short* Kb_h = kT_h + (size_t)cb * DK * CHUNK;
  const unsigned short* Kb_l = kT_l + (size_t)cb * DK * CHUNK;

  // stage kT once: [64 n][128 t], source slot-swizzled (slot ^= n&15)
#pragma unroll
  for (int it = 0; it < 4; ++it) {
    const int tk = it * 256 + tid;      // 0..1023
    const int n = tk >> 4, slot = tk & 15;
    gload16(&Kb_h[(size_t)n * CHUNK + ((slot ^ (n & 15)) << 3)], &Kh[tk * 8]);
    gload16(&Kb_l[(size_t)n * CHUNK + ((slot ^ (n & 15)) << 3)], &Kl[tk * 8]);
  }

  float4_t acc[4][2];
#pragma unroll
  for (int i = 0; i < 4; ++i)
#pragma unroll
    for (int j = 0; j < 2; ++j) acc[i][j] = (float4_t)0.0f;

  for (int ks = 0; ks < 4; ++ks) {
    const int k0 = ks * 32;
#pragma unroll
    for (int q = 0; q < 2; ++q) {
      const int flat = (q * 256 + tid) * 8;
      const int row = flat >> 5, col = flat & 31;
      gload16(&Ab_h[(size_t)row * CHUNK + k0 + col], &Ah[flat]);
      gload16(&Ab_l[(size_t)row * CHUNK + k0 + col], &Al[flat]);
    }
    __syncthreads();

    short8_t a_hi[4], a_lo[4], b_hi[2], b_lo[2];
#pragma unroll
    for (int i = 0; i < 4; ++i) {
      const int ar = (wm + i * 16 + fm) * 32 + fk;
      a_hi[i] = *(const short8_t*)&Ah[ar];
      a_lo[i] = *(const short8_t*)&Al[ar];
    }
#pragma unroll
    for (int j = 0; j < 2; ++j) {
      const int n = wn + j * 16 + fm;
      const int slot = (k0 + fk) >> 3;
      const int addr = n * CHUNK + ((slot ^ (n & 15)) << 3);
      b_hi[j] = *(const short8_t*)&Kh[addr];
      b_lo[j] = *(const short8_t*)&Kl[addr];
    }
#pragma unroll
    for (int i = 0; i < 4; ++i)
#pragma unroll
      for (int j = 0; j < 2; ++j) {
        acc[i][j] = __builtin_amdgcn_mfma_f32_16x16x32_bf16(a_hi[i], b_hi[j], acc[i][j], 0, 0, 0);
        acc[i][j] = __builtin_amdgcn_mfma_f32_16x16x32_bf16(a_lo[i], b_hi[j], acc[i][j], 0, 0, 0);
        acc[i][j] = __builtin_amdgcn_mfma_f32_16x16x32_bf16(a_hi[i], b_lo[j], acc[i][j], 0, 0, 0);
      }
    __syncthreads();
  }

#pragma unroll
  for (int j = 0; j < 2; ++j) {
    const int n = wn + j * 16 + fm;
    const float pj = pend[(cb >> 2) * 256 + (cb & 3) * 64 + n];
#pragma unroll
    for (int i = 0; i < 4; ++i) {
#pragma unroll
      for (int r = 0; r < 4; ++r) {
        const int dd = dt * 128 + wm + i * 16 + (lane >> 4) * 4 + r;
        W_ws[((size_t)cb * DV + dd) * DK + n] = acc[i][j][r] * pj;
      }
    }
  }
}

// ---------------------------------------------------------------------------
// K4: sequential state scan over chunks.  Emits pre-update state S_c as
// split-bf16 (Sh/Sl) for out_mfma's uniform global_load_lds staging.
// ---------------------------------------------------------------------------
__global__ __launch_bounds__(256) void scan_kernel(
    const float* __restrict__ W_ws, const float* __restrict__ pend,
    unsigned short* __restrict__ Sh, unsigned short* __restrict__ Sl)
{
  const int flat = blockIdx.x * 256 + threadIdx.x;
  const int n = flat & 63;
  const int bd = flat >> 6;
  const int b = bd >> 9;
  float s = 0.0f;
  for (int c = 0; c < NCH; ++c) {
    const int off = c * 131072 + flat;
    const float w = W_ws[off];
    const unsigned short h = f2bf(s);
    Sh[off] = h;
    Sl[off] = f2bf(s - bf2f(h));
    s = s * pend[c * 256 + b * 64 + n] + w;
  }
}

// ---------------------------------------------------------------------------
// K6: y = [A|q_t] @ [v ; S^T].  3 uniform K=64 XOR-swizzled steps.
// XCD-grouped 1D grid (4 nt-blocks of one (c,b) share an XCD's L2).
// ---------------------------------------------------------------------------
__global__ __launch_bounds__(256) void out_mfma_kernel(
    const unsigned short* __restrict__ Acat_h, const unsigned short* __restrict__ Acat_l,
    const unsigned short* __restrict__ Bt_h, const unsigned short* __restrict__ Bt_l,
    const unsigned short* __restrict__ Sh, const unsigned short* __restrict__ Sl,
    float* __restrict__ out)
{
  __shared__ __align__(16) unsigned short Ah[128 * 64];
  __shared__ __align__(16) unsigned short Al[128 * 64];
  __shared__ __align__(16) unsigned short Bh[128 * 64];
  __shared__ __align__(16) unsigned short Bl[128 * 64];

  const int bd = blockIdx.x;
  const int cb = (bd >> 5) * 8 + (bd & 7);
  const int nt = (bd >> 3) & 3;
  const int c = cb >> 2, b = cb & 3;
  const int tid  = threadIdx.x;
  const int wave = tid >> 6, lane = tid & 63;
  const int wm   = (wave & 1) * 64, wn = (wave >> 1) * 64;
  const int fm   = lane & 15;
  const int fk   = (lane >> 4) * 8;

  const unsigned short* Ab_h = Acat_h + (size_t)cb * CHUNK * KCAT;
  const unsigned short* Ab_l = Acat_l + (size_t)cb * CHUNK * KCAT;
  const unsigned short* Bb_h = Bt_h + ((size_t)cb * DV + nt * 128) * CHUNK;
  const unsigned short* Bb_l = Bt_l + ((size_t)cb * DV + nt * 128) * CHUNK;
  const unsigned short* Sb_h = Sh + ((size_t)cb * DV + nt * 128) * DK;
  const unsigned short* Sb_l = Sl + ((size_t)cb * DV + nt * 128) * DK;

  const int srow = tid >> 3;          // 0..31
  const int scolB = (tid & 7) * 16;
  const int sc = (scolB ^ ((srow & 7) << 4)) >> 1;   // halfs
  const int sdst = srow * 64 + (scolB >> 1);

  float4_t acc[4][4];
#pragma unroll
  for (int i = 0; i < 4; ++i)
#pragma unroll
    for (int j = 0; j < 4; ++j) acc[i][j] = (float4_t)0.0f;

  for (int ks = 0; ks < 3; ++ks) {
    const int k0 = ks * 64;
#pragma unroll
    for (int q = 0; q < 4; ++q) {
      const int row = q * 32 + srow;
      const int dst = q * 2048 + sdst;
      gload16(&Ab_h[(size_t)row * KCAT + k0 + sc], &Ah[dst]);
      gload16(&Ab_l[(size_t)row * KCAT + k0 + sc], &Al[dst]);
      if (ks < 2) {
        gload16(&Bb_h[(size_t)row * CHUNK + k0 + sc], &Bh[dst]);
        gload16(&Bb_l[(size_t)row * CHUNK + k0 + sc], &Bl[dst]);
      } else {
        gload16(&Sb_h[(size_t)row * DK + sc], &Bh[dst]);
        gload16(&Sb_l[(size_t)row * DK + sc], &Bl[dst]);
      }
    }
    __syncthreads();

#pragma unroll
    for (int ksub = 0; ksub < 2; ++ksub) {
      short8_t a_hi[4], a_lo[4], b_hi[4], b_lo[4];
#pragma unroll
      for (int i = 0; i < 4; ++i) {
        const int r = wm + i * 16 + fm;
        const int ar = r * 64 + ((ksub * 32 + fk) ^ ((r & 7) << 3));
        a_hi[i] = *(const short8_t*)&Ah[ar];
        a_lo[i] = *(const short8_t*)&Al[ar];
      }
#pragma unroll
      for (int j = 0; j < 4; ++j) {
        const int r = wn + j * 16 + fm;
        const int br = r * 64 + ((ksub * 32 + fk) ^ ((r & 7) << 3));
        b_hi[j] = *(const short8_t*)&Bh[br];
        b_lo[j] = *(const short8_t*)&Bl[br];
      }
      __builtin_amdgcn_s_setprio(1);
#pragma unroll
      for (int i = 0; i < 4; ++i)
#pragma unroll
        for (int j = 0; j < 4; ++j) {
          acc[i][j] = __builtin_amdgcn_mfma_f32_16x16x32_bf16(a_hi[i], b_hi[j], acc[i][j], 0, 0, 0);
          acc[i][j] = __builtin_amdgcn_mfma_f32_16x16x32_bf16(a_lo[i], b_hi[j], acc[i][j], 0, 0, 0);
          acc[i][j] = __builtin_amdgcn_mfma_f32_16x16x32_bf16(a_hi[i], b_lo[j], acc[i][j], 0, 0, 0);
        }
      __builtin_amdgcn_s_setprio(0);
    }
    __syncthreads();
  }

#pragma unroll
  for (int j = 0; j < 4; ++j) {
    const int d = nt * 128 + wn + j * 16 + fm;
#pragma unroll
    for (int i = 0; i < 4; ++i) {
#pragma unroll
      for (int r = 0; r < 4; ++r) {
        const int t = c * CHUNK + wm + i * 16 + (lane >> 4) * 4 + r;
        out[((size_t)t * B_DIM + b) * DV + d] = acc[i][j][r];
      }
    }
  }
}

// ---------------------------------------------------------------------------
extern "C" void kernel_launch(void* const* d_in, const int* in_sizes, int n_in,
                              void* d_out, int out_size, void* d_ws, size_t ws_size,
                              hipStream_t stream)
{
  const float* x  = (const float*)d_in[0];
  const float* Wv = (const float*)d_in[1];
  const float* bv = (const float*)d_in[2];
  const float* Wk = (const float*)d_in[3];
  const float* bk = (const float*)d_in[4];
  const float* Wq = (const float*)d_in[5];
  const float* bq = (const float*)d_in[6];
  const float* Wa = (const float*)d_in[7];
  const float* ba = (const float*)d_in[8];
  float* out = (float*)d_out;

  // ---- workspace layout ----
  float* ws   = (float*)d_ws;
  // Bt occupies the first 64 MB, written directly by proj.
  unsigned short* Bt_h = (unsigned short*)ws;               // 16,777,216 us
  unsigned short* Bt_l = Bt_h + (size_t)NCH * B_DIM * DV * CHUNK;
  float* k_ws = ws + (size_t)ROWS * DV;                     //  2,097,152 f (raw k)
  float* a_ws = k_ws + (size_t)ROWS * DK;                   //  2,097,152 f
  float* pend = a_ws + (size_t)ROWS * DK;                   //     16,384 f
  float* W_ws = pend + NCH * B_DIM * DK;                    //  8,388,608 f
  float* bcat = W_ws + (size_t)NCH * B_DIM * DV * DK;       //        768 f
  unsigned short* Acat_h = (unsigned short*)(bcat + NPAD);  //  6,291,456 us
  unsigned short* Acat_l = Acat_h + (size_t)NCH * B_DIM * CHUNK * KCAT;
  unsigned short* uni = Acat_l + (size_t)NCH * B_DIM * CHUNK * KCAT;
  // union: fp16 proj staging (dead after proj_mfma)
  unsigned short* xh = uni;                                 // 16,777,216 us
  unsigned short* wh = xh + (size_t)ROWS * INDIM;           //    393,216 us
  // q_ws: fp32 q staging at uni+36MB bytes (beyond xh+wh; no S overlap)
  float* q_ws = (float*)(uni + (size_t)18 * 1024 * 1024);   //  2,097,152 f
  // kT: split-bf16 k_t^T [cb][n][t], after q_ws (uni+44MB..52MB bytes)
  unsigned short* kT_h = (unsigned short*)(q_ws + (size_t)ROWS * DK);
  unsigned short* kT_l = kT_h + (size_t)NCH * B_DIM * DK * CHUNK;
  // Sh/Sl: split-bf16 state over dead xh (uni+0..32MB bytes)
  unsigned short* S_h = uni;                                //  8,388,608 us
  unsigned short* S_l = S_h + (size_t)NCH * B_DIM * DV * DK;

  cast_kernel<<<16384 + 384, 256, 0, stream>>>(
      x, Wv, Wk, Wq, Wa, bv, bk, bq, ba, xh, wh, bcat);
  proj_mfma_kernel<<<(ROWS / 128) * (NPAD / 128), 256, 0, stream>>>(
      xh, wh, bcat, Bt_h, Bt_l, k_ws, q_ws, a_ws);
  prep_kernel<<<dim3(NCH, B_DIM), 512, 0, stream>>>(
      a_ws, k_ws, q_ws, Acat_h, Acat_l, kT_h, kT_l, pend);
  wchunk_mfma_kernel<<<NCH * B_DIM * 4, 256, 0, stream>>>(
      Bt_h, Bt_l, kT_h, kT_l, pend, W_ws);
  scan_kernel<<<(B_DIM * DV * DK) / 256, 256, 0, stream>>>(
      W_ws, pend, S_h, S_l);
  out_mfma_kernel<<<NCH * B_DIM * 4, 256, 0, stream>>>(
      Acat_h, Acat_l, Bt_h, Bt_l, S_h, S_l, out);
}